// Round 1
// baseline (19248.361 us; speedup 1.0000x reference)
//
#include <hip/hip_runtime.h>
#include <math.h>

// FCOS RPN head, fp32 baseline. R1: correctness-first.
// Pipeline per level: cls tower (4x conv+GN+relu) -> score/ctr convs,
// box tower -> bbox conv, decode scores/boxes, exact top-1000 (radix hist +
// boundary ranking), then class-aware NMS (100 serial argmax iterations).

#define CIN 256
#define KCLS 80
#define TOPKK 1000
#define NCAND 5000
#define MAXDET 100

// ---------------- weight repack: w(OC,256,3,3) -> wT[(ic*9+k)*OCpad + oc] ---
__global__ void k_repack(const float* __restrict__ w, float* __restrict__ wT,
                         int OC, int OCpad) {
  int i = blockIdx.x * blockDim.x + threadIdx.x;
  int tot = OC * CIN * 9;
  if (i >= tot) return;
  int oc = i / (CIN * 9);
  int r = i % (CIN * 9);  // ic*9+k
  wT[(size_t)r * OCpad + oc] = w[i];
}

// ---------------- conv3x3, pad=1, Cin=256 -----------------------------------
// block: 256 thr = 4 waves. spatial tile 8x8 (64 lanes), each wave 16 ocs.
__global__ __launch_bounds__(256) void k_conv(
    const float* __restrict__ in, const float* __restrict__ wT,
    const float* __restrict__ bias, float* __restrict__ out,
    int H, int W, int OC, int OCpad, int tilesX) {
  const int HW = H * W;
  const int n = blockIdx.z;
  const int ocBlk = blockIdx.y * 64;
  const int tx0 = (blockIdx.x % tilesX) * 8;
  const int ty0 = (blockIdx.x / tilesX) * 8;
  const int t = threadIdx.x;
  const int lane = t & 63;
  const int lx = lane & 7, ly = lane >> 3;
  const int ox = tx0 + lx, oy = ty0 + ly;
  const int wsel = __builtin_amdgcn_readfirstlane(ocBlk + (t >> 6) * 16);
  const bool wactive = (wsel < OCpad);  // wave-uniform

  __shared__ float sIn[8][10][10];
  float acc[16];
#pragma unroll
  for (int i = 0; i < 16; ++i) acc[i] = 0.f;
  const float* inN = in + (size_t)n * CIN * HW;

#pragma unroll 1
  for (int icc = 0; icc < CIN; icc += 8) {
    __syncthreads();
#pragma unroll 1
    for (int e = t; e < 800; e += 256) {
      int ic = e / 100, r = e % 100;
      int yy = r / 10, xx = r % 10;
      int gy = ty0 + yy - 1, gx = tx0 + xx - 1;
      float v = 0.f;
      if ((unsigned)gy < (unsigned)H && (unsigned)gx < (unsigned)W)
        v = inN[(size_t)(icc + ic) * HW + gy * W + gx];
      sIn[ic][yy][xx] = v;
    }
    __syncthreads();
    if (wactive) {
#pragma unroll 1
      for (int ic = 0; ic < 8; ++ic) {
        const float* wrow = wT + (size_t)((icc + ic) * 9) * OCpad + wsel;
#pragma unroll
        for (int k = 0; k < 9; ++k) {
          float iv = sIn[ic][ly + (k / 3)][lx + (k % 3)];
          const float4* wp = (const float4*)(wrow + (size_t)k * OCpad);
          float4 w0 = wp[0], w1 = wp[1], w2 = wp[2], w3 = wp[3];
          acc[0]  = fmaf(iv, w0.x, acc[0]);
          acc[1]  = fmaf(iv, w0.y, acc[1]);
          acc[2]  = fmaf(iv, w0.z, acc[2]);
          acc[3]  = fmaf(iv, w0.w, acc[3]);
          acc[4]  = fmaf(iv, w1.x, acc[4]);
          acc[5]  = fmaf(iv, w1.y, acc[5]);
          acc[6]  = fmaf(iv, w1.z, acc[6]);
          acc[7]  = fmaf(iv, w1.w, acc[7]);
          acc[8]  = fmaf(iv, w2.x, acc[8]);
          acc[9]  = fmaf(iv, w2.y, acc[9]);
          acc[10] = fmaf(iv, w2.z, acc[10]);
          acc[11] = fmaf(iv, w2.w, acc[11]);
          acc[12] = fmaf(iv, w3.x, acc[12]);
          acc[13] = fmaf(iv, w3.y, acc[13]);
          acc[14] = fmaf(iv, w3.z, acc[14]);
          acc[15] = fmaf(iv, w3.w, acc[15]);
        }
      }
    }
  }
  if (ox < W && oy < H && wactive) {
    float* outN = out + (size_t)n * OC * HW + (size_t)oy * W + ox;
#pragma unroll
    for (int i = 0; i < 16; ++i) {
      int oc = wsel + i;
      if (oc < OC) outN[(size_t)oc * HW] = acc[i] + bias[oc];
    }
  }
}

// ---------------- GroupNorm: partial sums (double) --------------------------
__global__ __launch_bounds__(256) void k_gn_part(const float* __restrict__ x,
                                                 double* __restrict__ part,
                                                 int HW) {
  int ng = blockIdx.x;  // n*32+g
  int sp = blockIdx.y;  // 0..7
  int n = ng >> 5, g = ng & 31;
  size_t base = ((size_t)n * CIN + g * 8) * HW;
  int len = 8 * HW;
  int chunk = (len + 7) / 8;
  int lo = sp * chunk;
  int hi = lo + chunk; if (hi > len) hi = len;
  double s = 0.0, ss = 0.0;
  for (int i = lo + threadIdx.x; i < hi; i += 256) {
    float v = x[base + i];
    s += v; ss += (double)v * v;
  }
  __shared__ double rs[256], rss[256];
  rs[threadIdx.x] = s; rss[threadIdx.x] = ss;
  __syncthreads();
  for (int off = 128; off > 0; off >>= 1) {
    if (threadIdx.x < off) {
      rs[threadIdx.x] += rs[threadIdx.x + off];
      rss[threadIdx.x] += rss[threadIdx.x + off];
    }
    __syncthreads();
  }
  if (threadIdx.x == 0) {
    part[(ng * 8 + sp) * 2] = rs[0];
    part[(ng * 8 + sp) * 2 + 1] = rss[0];
  }
}

__global__ void k_gn_coef(const double* __restrict__ part,
                          const float* __restrict__ gs, const float* __restrict__ gb,
                          float* __restrict__ cA, float* __restrict__ cB, int HW) {
  int ng = threadIdx.x;
  if (ng >= 64) return;
  double s = 0.0, ss = 0.0;
  for (int k = 0; k < 8; ++k) {
    s += part[(ng * 8 + k) * 2];
    ss += part[(ng * 8 + k) * 2 + 1];
  }
  int len = 8 * HW;
  double mu = s / len;
  double var = ss / len - mu * mu;
  double rsq = 1.0 / sqrt(var + 1e-5);
  int n = ng >> 5, g = ng & 31;
  for (int cc = 0; cc < 8; ++cc) {
    int c = g * 8 + cc;
    double A = rsq * (double)gs[c];
    cA[n * CIN + c] = (float)A;
    cB[n * CIN + c] = (float)((double)gb[c] - mu * A);
  }
}

__global__ void k_gn_apply(float* __restrict__ x, const float* __restrict__ cA,
                           const float* __restrict__ cB, int HW) {
  size_t i = (size_t)blockIdx.x * blockDim.x + threadIdx.x;
  size_t tot = (size_t)2 * CIN * HW;
  if (i >= tot) return;
  int c = (int)((i / HW) & 255);
  int n = (int)(i / ((size_t)CIN * HW));
  int idx = n * CIN + c;
  x[i] = fmaxf(0.f, fmaf(x[i], cA[idx], cB[idx]));
}

// ---------------- decode: scores (n,HW*80) + boxes (n,HW,4) -----------------
__global__ void k_decode(const float* __restrict__ logits, const float* __restrict__ ctr,
                         const float* __restrict__ reg, const float* __restrict__ scales,
                         int lvl, int H, int W, float stride,
                         float* __restrict__ sf, float* __restrict__ boxes) {
  int HW = H * W;
  size_t tot = (size_t)2 * HW * KCLS;
  size_t i = (size_t)blockIdx.x * blockDim.x + threadIdx.x;
  if (i >= tot) return;
  int c = (int)(i % KCLS);
  int a = (int)((i / KCLS) % HW);
  int n = (int)(i / ((size_t)HW * KCLS));
  float lg = logits[((size_t)n * KCLS + c) * HW + a];
  float ct = ctr[(size_t)n * HW + a];
  float s1 = 1.f / (1.f + expf(-lg));
  float s2 = 1.f / (1.f + expf(-ct));
  sf[i] = sqrtf(s1 * s2);
  if (c == 0) {
    float scale = scales[lvl];
    int x = a % W, y = a / W;
    float px = (x + 0.5f) * stride, py = (y + 0.5f) * stride;
    float r0 = fmaxf(0.f, scale * reg[((size_t)n * 4 + 0) * HW + a]);
    float r1 = fmaxf(0.f, scale * reg[((size_t)n * 4 + 1) * HW + a]);
    float r2 = fmaxf(0.f, scale * reg[((size_t)n * 4 + 2) * HW + a]);
    float r3 = fmaxf(0.f, scale * reg[((size_t)n * 4 + 3) * HW + a]);
    float* bp = boxes + ((size_t)n * HW + a) * 4;
    bp[0] = px - r0 * stride; bp[1] = py - r1 * stride;
    bp[2] = px + r2 * stride; bp[3] = py + r3 * stride;
  }
}

// ---------------- exact top-1000 via 2-level 12-bit radix -------------------
__global__ void k_hist1(const float* __restrict__ sf, unsigned* __restrict__ hist,
                        int M) {
  int n = blockIdx.y;
  const float* s = sf + (size_t)n * M;
  unsigned* h = hist + n * 1024;
  __shared__ unsigned lh[1024];
  for (int i = threadIdx.x; i < 1024; i += blockDim.x) lh[i] = 0;
  __syncthreads();
  for (int i = blockIdx.x * blockDim.x + threadIdx.x; i < M;
       i += gridDim.x * blockDim.x) {
    unsigned key = __float_as_uint(s[i]);
    unsigned b = key >> 20; if (b > 1023u) b = 1023u;
    atomicAdd(&lh[b], 1u);
  }
  __syncthreads();
  for (int i = threadIdx.x; i < 1024; i += blockDim.x)
    if (lh[i]) atomicAdd(&h[i], lh[i]);
}

// ctl: [0..1]=b1 per n, [2..3]=m1 per n, [4..5]=P(24-bit prefix) per n
__global__ void k_resolve1(const unsigned* __restrict__ hist, unsigned* __restrict__ ctl) {
  int n = threadIdx.x;
  if (n >= 2) return;
  const unsigned* h = hist + n * 1024;
  unsigned acc = 0; int b = 1023;
  for (; b > 0; --b) { acc += h[b]; if (acc >= TOPKK) break; }
  if (acc < TOPKK) { acc += h[0]; b = 0; }
  ctl[n] = (unsigned)b;
  ctl[2 + n] = acc - h[b];
}

__global__ void k_hist2(const float* __restrict__ sf, const unsigned* __restrict__ ctl,
                        unsigned* __restrict__ hist2, int M) {
  int n = blockIdx.y;
  unsigned b1 = ctl[n];
  const float* s = sf + (size_t)n * M;
  unsigned* h = hist2 + n * 4096;
  __shared__ unsigned lh[4096];
  for (int i = threadIdx.x; i < 4096; i += blockDim.x) lh[i] = 0;
  __syncthreads();
  for (int i = blockIdx.x * blockDim.x + threadIdx.x; i < M;
       i += gridDim.x * blockDim.x) {
    unsigned key = __float_as_uint(s[i]);
    if ((key >> 20) == b1) atomicAdd(&lh[(key >> 8) & 0xFFFu], 1u);
  }
  __syncthreads();
  for (int i = threadIdx.x; i < 4096; i += blockDim.x)
    if (lh[i]) atomicAdd(&h[i], lh[i]);
}

__global__ void k_resolve2(const unsigned* __restrict__ hist2, unsigned* __restrict__ ctl) {
  int n = threadIdx.x;
  if (n >= 2) return;
  unsigned b1 = ctl[n];
  unsigned acc = ctl[2 + n];
  const unsigned* h = hist2 + n * 4096;
  int b = 4095;
  for (; b > 0; --b) { acc += h[b]; if (acc >= TOPKK) break; }
  if (acc < TOPKK) b = 0;
  ctl[4 + n] = (b1 << 12) | (unsigned)b;
}

__device__ inline void write_cand(int n, int slot, float v, int idx,
                                  const float* __restrict__ boxes, int HW,
                                  float* cb, float* cob, float* csc, float* ccl) {
  int a = idx / KCLS, c = idx - a * KCLS;
  const float* bp = boxes + ((size_t)n * HW + a) * 4;
  float off = (float)c * 1e4f;
  size_t g = (size_t)n * NCAND + slot;
  float b0 = bp[0], b1 = bp[1], b2 = bp[2], b3 = bp[3];
  cb[g * 4 + 0] = b0; cb[g * 4 + 1] = b1; cb[g * 4 + 2] = b2; cb[g * 4 + 3] = b3;
  cob[g * 4 + 0] = b0 + off; cob[g * 4 + 1] = b1 + off;
  cob[g * 4 + 2] = b2 + off; cob[g * 4 + 3] = b3 + off;
  csc[g] = (v > 0.05f) ? v : 0.f;
  ccl[g] = (float)c;
}

// cnts: [0..1]=strictly-above count per n, [2..3]=equal-bin count per n
__global__ void k_compact(const float* __restrict__ sf, const unsigned* __restrict__ ctl,
                          unsigned* __restrict__ cnts, float* __restrict__ eqV,
                          unsigned* __restrict__ eqI, const float* __restrict__ boxes,
                          float* cb, float* cob, float* csc, float* ccl,
                          int M, int lvlOff) {
  int n = blockIdx.y;
  int HW = M / KCLS;
  const float* s = sf + (size_t)n * M;
  unsigned P = ctl[4 + n];
  for (int i = blockIdx.x * blockDim.x + threadIdx.x; i < M;
       i += gridDim.x * blockDim.x) {
    float v = s[i];
    unsigned k24 = __float_as_uint(v) >> 8;
    if (k24 < P) continue;
    if (k24 > P) {
      unsigned slot = atomicAdd(&cnts[n], 1u);
      write_cand(n, lvlOff + (int)slot, v, i, boxes, HW, cb, cob, csc, ccl);
    } else {
      unsigned e = atomicAdd(&cnts[2 + n], 1u);
      if (e < 2048u) { eqV[n * 2048 + e] = v; eqI[n * 2048 + e] = (unsigned)i; }
    }
  }
}

__global__ void k_eq(const float* __restrict__ eqV, const unsigned* __restrict__ eqI,
                     const unsigned* __restrict__ cnts, const float* __restrict__ boxes,
                     float* cb, float* cob, float* csc, float* ccl, int M, int lvlOff) {
  int n = blockIdx.x;
  int HW = M / KCLS;
  int above = (int)cnts[n];
  unsigned ec = cnts[2 + n];
  int E = ec < 2048u ? (int)ec : 2048;
  int r = TOPKK - above;
  for (int e = threadIdx.x; e < E; e += blockDim.x) {
    float v = eqV[n * 2048 + e];
    unsigned idx = eqI[n * 2048 + e];
    int rank = 0;
    for (int j = 0; j < E; ++j) {
      float vj = eqV[n * 2048 + j];
      unsigned ij = eqI[n * 2048 + j];
      if (vj > v || (vj == v && ij < idx)) rank++;
    }
    if (rank < r)
      write_cand(n, lvlOff + above + rank, v, (int)idx, boxes, HW, cb, cob, csc, ccl);
  }
}

// ---------------- NMS: 1 block per batch, 100 serial iterations -------------
__global__ __launch_bounds__(256) void k_nms(
    const float* __restrict__ cbox, const float* __restrict__ cobx,
    const float* __restrict__ cscore, const float* __restrict__ ccls,
    float* __restrict__ out) {
  int n = blockIdx.x;
  __shared__ float s[NCAND];
  __shared__ float area[NCAND];
  __shared__ float redV[4];
  __shared__ int redI[4];
  __shared__ float curV;
  __shared__ int curI;
  const float4* ob4 = (const float4*)(cobx + (size_t)n * NCAND * 4);
  for (int j = threadIdx.x; j < NCAND; j += 256) {
    s[j] = cscore[n * NCAND + j];
    float4 b = ob4[j];
    area[j] = fmaxf(b.z - b.x, 0.f) * fmaxf(b.w - b.y, 0.f);
  }
  __syncthreads();
  for (int it = 0; it < MAXDET; ++it) {
    float mv = -1.f; int mi = 0;
    for (int j = threadIdx.x; j < NCAND; j += 256) {
      float v = s[j];
      if (v > mv) { mv = v; mi = j; }
    }
    for (int off = 1; off < 64; off <<= 1) {
      float ov = __shfl_xor(mv, off);
      int oi = __shfl_xor(mi, off);
      if (ov > mv || (ov == mv && oi < mi)) { mv = ov; mi = oi; }
    }
    if ((threadIdx.x & 63) == 0) { redV[threadIdx.x >> 6] = mv; redI[threadIdx.x >> 6] = mi; }
    __syncthreads();
    if (threadIdx.x == 0) {
      float bv = redV[0]; int bi = redI[0];
      for (int w = 1; w < 4; ++w)
        if (redV[w] > bv || (redV[w] == bv && redI[w] < bi)) { bv = redV[w]; bi = redI[w]; }
      curV = bv; curI = bi;
    }
    __syncthreads();
    float si = curV; int i = curI;
    bool valid = si > 0.f;
    float4 bi4 = ob4[i];
    float ai = area[i];
    if (valid) {
      for (int j = threadIdx.x; j < NCAND; j += 256) {
        float4 bj = ob4[j];
        float iw = fmaxf(fminf(bi4.z, bj.z) - fmaxf(bi4.x, bj.x), 0.f);
        float ih = fmaxf(fminf(bi4.w, bj.w) - fmaxf(bi4.y, bj.y), 0.f);
        float inter = iw * ih;
        float iou = inter / fmaxf(ai + area[j] - inter, 1e-6f);
        if (iou > 0.6f || j == i) s[j] = 0.f;
      }
    }
    if (threadIdx.x == 0) {
      float* o = out + ((size_t)n * MAXDET + it) * 6;
      if (valid) {
        const float* bb = cbox + ((size_t)n * NCAND + i) * 4;
        o[0] = bb[0]; o[1] = bb[1]; o[2] = bb[2]; o[3] = bb[3];
        o[4] = si; o[5] = ccls[n * NCAND + i];
      } else {
        o[0] = o[1] = o[2] = o[3] = o[4] = o[5] = 0.f;
      }
    }
    __syncthreads();
  }
}

// ---------------- host orchestration ----------------------------------------
extern "C" void kernel_launch(void* const* d_in, const int* in_sizes, int n_in,
                              void* d_out, int out_size, void* d_ws, size_t ws_size,
                              hipStream_t stream) {
  const float* feats[5] = {(const float*)d_in[0], (const float*)d_in[1],
                           (const float*)d_in[2], (const float*)d_in[3],
                           (const float*)d_in[4]};
  const float* cls_w = (const float*)d_in[5];
  const float* cls_b = (const float*)d_in[6];
  const float* cls_gs = (const float*)d_in[7];
  const float* cls_gb = (const float*)d_in[8];
  const float* box_w = (const float*)d_in[9];
  const float* box_b = (const float*)d_in[10];
  const float* box_gs = (const float*)d_in[11];
  const float* box_gb = (const float*)d_in[12];
  const float* score_w = (const float*)d_in[13];
  const float* score_b = (const float*)d_in[14];
  const float* bbox_w = (const float*)d_in[15];
  const float* bbox_b = (const float*)d_in[16];
  const float* ctr_w = (const float*)d_in[17];
  const float* ctr_b = (const float*)d_in[18];
  const float* scales = (const float*)d_in[19];

  static const int LH[5] = {100, 50, 25, 13, 7};
  static const int LW[5] = {152, 76, 38, 19, 10};
  static const int LS[5] = {8, 16, 32, 64, 128};

  // ws layout in floats (all 16B aligned)
  float* ws = (float*)d_ws;
  const size_t A_off = 0;
  const size_t B_off = A_off + 7782400;       // 2*256*15200
  const size_t LG_off = B_off + 7782400;      // 2*80*15200
  const size_t CT_off = LG_off + 2432000;     // 2*15200
  const size_t RG_off = CT_off + 30400;       // 2*4*15200
  const size_t SF_off = RG_off + 121600;      // 2*15200*80
  const size_t BX_off = SF_off + 2432000;     // 2*15200*4
  const size_t CA_off = BX_off + 121600;      // 512
  const size_t CB_off = CA_off + 512;
  const size_t PART_off = CB_off + 512;       // 1024 doubles = 2048 floats
  const size_t WTC_off = PART_off + 2048;     // 4*2304*256
  const size_t WTB_off = WTC_off + 2359296;
  const size_t WTS_off = WTB_off + 2359296;   // 2304*80
  const size_t WTBB_off = WTS_off + 184320;   // 2304*16
  const size_t WTCT_off = WTBB_off + 36864;   // 2304*16
  const size_t CBX_off = WTCT_off + 36864;    // 2*5000*4
  const size_t COB_off = CBX_off + 40000;
  const size_t CSC_off = COB_off + 40000;     // 2*5000
  const size_t CCL_off = CSC_off + 10000;
  const size_t H1_off = CCL_off + 10000;      // 2*1024 u32
  const size_t H2_off = H1_off + 2048;        // 2*4096 u32
  const size_t CNT_off = H2_off + 8192;       // 8 u32
  const size_t CTL_off = CNT_off + 8;         // 8 u32
  const size_t EV_off = CTL_off + 8;          // 2*2048 f32
  const size_t EI_off = EV_off + 4096;        // 2*2048 u32

  float* A = ws + A_off;
  float* B = ws + B_off;
  float* LG = ws + LG_off;
  float* CT = ws + CT_off;
  float* RG = ws + RG_off;
  float* SF = ws + SF_off;
  float* BX = ws + BX_off;
  float* cAp = ws + CA_off;
  float* cBp = ws + CB_off;
  double* partP = (double*)(ws + PART_off);
  float* wtc = ws + WTC_off;
  float* wtb = ws + WTB_off;
  float* wts = ws + WTS_off;
  float* wtbb = ws + WTBB_off;
  float* wtct = ws + WTCT_off;
  float* CBXp = ws + CBX_off;
  float* COBp = ws + COB_off;
  float* CSCp = ws + CSC_off;
  float* CCLp = ws + CCL_off;
  unsigned* h1p = (unsigned*)(ws + H1_off);
  unsigned* h2p = (unsigned*)(ws + H2_off);
  unsigned* cntp = (unsigned*)(ws + CNT_off);
  unsigned* ctlp = (unsigned*)(ws + CTL_off);
  float* EVp = ws + EV_off;
  unsigned* EIp = (unsigned*)(ws + EI_off);

  // zero the padded small-weight regions once per call
  hipMemsetAsync(ws + WTBB_off, 0, (36864 + 36864) * sizeof(float), stream);

  // repack weights
  for (int l = 0; l < 4; ++l) {
    hipLaunchKernelGGL(k_repack, dim3((256 * 2304 + 255) / 256), dim3(256), 0, stream,
                       cls_w + (size_t)l * 256 * 2304, wtc + (size_t)l * 2304 * 256, 256, 256);
    hipLaunchKernelGGL(k_repack, dim3((256 * 2304 + 255) / 256), dim3(256), 0, stream,
                       box_w + (size_t)l * 256 * 2304, wtb + (size_t)l * 2304 * 256, 256, 256);
  }
  hipLaunchKernelGGL(k_repack, dim3((80 * 2304 + 255) / 256), dim3(256), 0, stream,
                     score_w, wts, 80, 80);
  hipLaunchKernelGGL(k_repack, dim3((4 * 2304 + 255) / 256), dim3(256), 0, stream,
                     bbox_w, wtbb, 4, 16);
  hipLaunchKernelGGL(k_repack, dim3((1 * 2304 + 255) / 256), dim3(256), 0, stream,
                     ctr_w, wtct, 1, 16);

  for (int l = 0; l < 5; ++l) {
    const int H = LH[l], W = LW[l];
    const int HW = H * W;
    const int M = HW * KCLS;
    const int tilesX = (W + 7) / 8, tilesY = (H + 7) / 8;

    auto conv = [&](const float* in, const float* wTp, const float* bp, float* outp,
                    int OC, int OCpad) {
      dim3 g(tilesX * tilesY, (OC + 63) / 64, 2);
      hipLaunchKernelGGL(k_conv, g, dim3(256), 0, stream, in, wTp, bp, outp,
                         H, W, OC, OCpad, tilesX);
    };
    auto gn = [&](float* buf, const float* gsp, const float* gbp) {
      hipLaunchKernelGGL(k_gn_part, dim3(64, 8), dim3(256), 0, stream, buf, partP, HW);
      hipLaunchKernelGGL(k_gn_coef, dim3(1), dim3(64), 0, stream, partP, gsp, gbp,
                         cAp, cBp, HW);
      size_t tot = (size_t)2 * CIN * HW;
      hipLaunchKernelGGL(k_gn_apply, dim3((unsigned)((tot + 255) / 256)), dim3(256),
                         0, stream, buf, cAp, cBp, HW);
    };

    // cls tower -> B
    conv(feats[l], wtc + 0 * 589824, cls_b + 0, A, 256, 256);
    gn(A, cls_gs + 0, cls_gb + 0);
    conv(A, wtc + 1 * 589824, cls_b + 256, B, 256, 256);
    gn(B, cls_gs + 256, cls_gb + 256);
    conv(B, wtc + 2 * 589824, cls_b + 512, A, 256, 256);
    gn(A, cls_gs + 512, cls_gb + 512);
    conv(A, wtc + 3 * 589824, cls_b + 768, B, 256, 256);
    gn(B, cls_gs + 768, cls_gb + 768);
    // heads on cls tower
    conv(B, wts, score_b, LG, 80, 80);
    conv(B, wtct, ctr_b, CT, 1, 16);
    // box tower -> B (cls_t consumed above)
    conv(feats[l], wtb + 0 * 589824, box_b + 0, A, 256, 256);
    gn(A, box_gs + 0, box_gb + 0);
    conv(A, wtb + 1 * 589824, box_b + 256, B, 256, 256);
    gn(B, box_gs + 256, box_gb + 256);
    conv(B, wtb + 2 * 589824, box_b + 512, A, 256, 256);
    gn(A, box_gs + 512, box_gb + 512);
    conv(A, wtb + 3 * 589824, box_b + 768, B, 256, 256);
    gn(B, box_gs + 768, box_gb + 768);
    conv(B, wtbb, bbox_b, RG, 4, 16);

    // decode scores + boxes
    size_t dtot = (size_t)2 * HW * KCLS;
    hipLaunchKernelGGL(k_decode, dim3((unsigned)((dtot + 255) / 256)), dim3(256), 0,
                       stream, LG, CT, RG, scales, l, H, W, (float)LS[l], SF, BX);

    // top-1000 exact
    hipMemsetAsync(ws + H1_off, 0, (2048 + 8192 + 8 + 8) * sizeof(float), stream);
    hipLaunchKernelGGL(k_hist1, dim3(256, 2), dim3(256), 0, stream, SF, h1p, M);
    hipLaunchKernelGGL(k_resolve1, dim3(1), dim3(64), 0, stream, h1p, ctlp);
    hipLaunchKernelGGL(k_hist2, dim3(256, 2), dim3(256), 0, stream, SF, ctlp, h2p, M);
    hipLaunchKernelGGL(k_resolve2, dim3(1), dim3(64), 0, stream, h2p, ctlp);
    hipLaunchKernelGGL(k_compact, dim3(256, 2), dim3(256), 0, stream, SF, ctlp, cntp,
                       EVp, EIp, BX, CBXp, COBp, CSCp, CCLp, M, l * TOPKK);
    hipLaunchKernelGGL(k_eq, dim3(2), dim3(256), 0, stream, EVp, EIp, cntp, BX,
                       CBXp, COBp, CSCp, CCLp, M, l * TOPKK);
  }

  hipLaunchKernelGGL(k_nms, dim3(2), dim3(256), 0, stream, CBXp, COBp, CSCp, CCLp,
                     (float*)d_out);
}

// Round 3
// 6847.536 us; speedup vs baseline: 2.8110x; 2.8110x over previous
//
#include <hip/hip_runtime.h>
#include <math.h>

// FCOS RPN head, fp32, R3: R2 + fix — fused GN+ReLU staging must store exact 0
// for out-of-bounds halo pixels (pad AFTER activation, not before).
// v_pk_fma_f32 packed fp32 conv, all levels batched per dispatch, GN partial
// sums fused into conv epilogue (fp64), ctr folded into score conv.

#define KCLS 80
#define TOPKK 1000
#define NCAND 5000
#define MAXDET 100
#define TOTHW 20267
#define TT 345

constexpr int cHa[5]  = {100, 50, 25, 13, 7};
constexpr int cWa[5]  = {152, 76, 38, 19, 10};
constexpr int cHWa[5] = {15200, 3800, 950, 247, 70};
constexpr int cPa[5]  = {0, 15200, 19000, 19950, 20197};
constexpr int cTXa[5] = {19, 10, 5, 3, 2};
constexpr int cPTa[5] = {0, 247, 317, 337, 343};
constexpr int cTa[5]  = {247, 70, 20, 6, 2};
constexpr float cSa[5] = {8.f, 16.f, 32.f, 64.f, 128.f};

typedef float f2 __attribute__((ext_vector_type(2)));

struct FeatPtrs { const float* p[5]; };

__device__ __forceinline__ int lvl_of_tile(int bx) {
  return (bx < 247) ? 0 : (bx < 317) ? 1 : (bx < 337) ? 2 : (bx < 343) ? 3 : 4;
}
__device__ __forceinline__ int lvl_of_pix(int gi) {
  return (gi < 15200) ? 0 : (gi < 19000) ? 1 : (gi < 19950) ? 2 : (gi < 20197) ? 3 : 4;
}

// acc.lo += p.lo*w.lo ; acc.hi += p.lo*w.hi   (broadcast p.lo)
__device__ __forceinline__ void pk_lo(f2& acc, f2 p, f2 w) {
  asm("v_pk_fma_f32 %0, %1, %2, %0 op_sel:[0,0,0] op_sel_hi:[0,1,1]"
      : "+v"(acc) : "v"(p), "s"(w));
}
// acc.lo += p.hi*w.lo ; acc.hi += p.hi*w.hi   (broadcast p.hi)
__device__ __forceinline__ void pk_hi(f2& acc, f2 p, f2 w) {
  asm("v_pk_fma_f32 %0, %1, %2, %0 op_sel:[1,0,0] op_sel_hi:[1,1,1]"
      : "+v"(acc) : "v"(p), "s"(w));
}

// ---------------- weight repack: w(OC,256,3,3) -> wT[(ic*9+k)*OCpad + ocOff+oc]
__global__ void k_repack(const float* __restrict__ w, float* __restrict__ wT,
                         int OC, int OCpad, int ocOff) {
  int i = blockIdx.x * blockDim.x + threadIdx.x;
  int tot = OC * 256 * 9;
  if (i >= tot) return;
  int oc = i / (256 * 9);
  int r = i % (256 * 9);
  wT[(size_t)r * OCpad + ocOff + oc] = w[i];
}

// ---------------- conv3x3 pad=1 Cin=256, all levels batched ------------------
// block: 256 thr = 4 waves; 8x8 spatial tile; wave -> 16 consecutive ocs.
template <bool FROM_FEATS, bool AFFINE, bool GN_PART, bool HEAD>
__global__ __launch_bounds__(256) void k_conv(
    FeatPtrs feats, const float* __restrict__ actIn, const float* __restrict__ wT,
    const float* __restrict__ bias1, const float* __restrict__ bias2,
    const float* __restrict__ cab, float* __restrict__ out,
    int outCH, int OC, int OCpad, double* __restrict__ part) {
  const int bx = blockIdx.x;
  const int l = lvl_of_tile(bx);
  const int tile = bx - cPTa[l];
  const int H = cHa[l], W = cWa[l], HW = cHWa[l];
  const int tx0 = (tile % cTXa[l]) * 8, ty0 = (tile / cTXa[l]) * 8;
  const int n = blockIdx.z;
  const int ocBlk = blockIdx.y * 64;
  const int t = threadIdx.x;
  const int lane = t & 63;
  const int lx = lane & 7, ly = lane >> 3;
  const int wsel = __builtin_amdgcn_readfirstlane(ocBlk + (t >> 6) * 16);
  const bool wactive = (wsel < OCpad);

  __shared__ float sInF[1604];

  const float* inN = FROM_FEATS
      ? feats.p[l] + (size_t)n * 256 * HW
      : actIn + 512 * (size_t)cPa[l] + (size_t)n * 256 * HW;
  const float* cabL = cab + (size_t)(l * 2 + n) * 512;

  // staging slot precompute (addressing hoisted out of the K loop)
  const float* sp[7];
  int sic[7];
  bool sinb[7], shas[7];
#pragma unroll
  for (int s = 0; s < 7; ++s) {
    int e = t + 256 * s;
    bool has = e < 1600;
    int ic = e / 100, r = e - ic * 100;
    int yy = r / 10, xx = r - yy * 10;
    int gy = ty0 + yy - 1, gx = tx0 + xx - 1;
    bool inb = has && ((unsigned)gy < (unsigned)H) && ((unsigned)gx < (unsigned)W);
    sp[s] = inN + (size_t)ic * HW + (size_t)gy * W + gx;
    sic[s] = ic; sinb[s] = inb; shas[s] = has;
  }

  f2 acc[8];
#pragma unroll
  for (int i = 0; i < 8; ++i) acc[i] = (f2)(0.f);

  float rv[7];
#pragma unroll
  for (int s = 0; s < 7; ++s) {
    rv[s] = sinb[s] ? *sp[s] : 0.f;
    sp[s] += (size_t)16 * HW;
  }

#pragma unroll 1
  for (int icc = 0; icc < 256; icc += 16) {
    __syncthreads();
#pragma unroll
    for (int s = 0; s < 7; ++s) {
      if (shas[s]) {
        float v = rv[s];
        if (AFFINE) {
          // FIX(R3): reference pads the POST-GN activation with zeros; apply
          // the affine+relu only to in-bounds pixels, keep OOB halo at 0.
          int c = icc + sic[s];
          v = sinb[s] ? fmaxf(0.f, fmaf(v, cabL[2 * c], cabL[2 * c + 1])) : 0.f;
        }
        sInF[t + 256 * s] = v;
      }
    }
    if (icc < 240) {
#pragma unroll
      for (int s = 0; s < 7; ++s) {
        if (shas[s]) {
          rv[s] = sinb[s] ? *sp[s] : 0.f;
          sp[s] += (size_t)16 * HW;
        }
      }
    }
    __syncthreads();
    if (wactive) {
#pragma unroll 4
      for (int ic = 0; ic < 16; ++ic) {
        const float* srow = sInF + ic * 100 + ly * 10 + lx;
        const float* wr0 = wT + (size_t)((icc + ic) * 9) * OCpad + wsel;
#pragma unroll
        for (int ky = 0; ky < 3; ++ky) {
          f2 p01, p23;
          __builtin_memcpy(&p01, srow + ky * 10, 8);
          __builtin_memcpy(&p23, srow + ky * 10 + 2, 8);
          const float* wr = wr0 + (size_t)(ky * 3) * OCpad;
#pragma unroll
          for (int j = 0; j < 8; ++j) { f2 w; __builtin_memcpy(&w, wr + 2 * j, 8); pk_lo(acc[j], p01, w); }
#pragma unroll
          for (int j = 0; j < 8; ++j) { f2 w; __builtin_memcpy(&w, wr + OCpad + 2 * j, 8); pk_hi(acc[j], p01, w); }
#pragma unroll
          for (int j = 0; j < 8; ++j) { f2 w; __builtin_memcpy(&w, wr + 2 * OCpad + 2 * j, 8); pk_lo(acc[j], p23, w); }
        }
      }
    }
  }

  const int ox = tx0 + lx, oy = ty0 + ly;
  const bool pvalid = (ox < W) && (oy < H);
  float y[16];
#pragma unroll
  for (int i = 0; i < 16; ++i) {
    int oc = wsel + i;
    float b;
    if (HEAD) b = (oc < 80) ? bias1[oc] : (oc == 80 ? bias2[0] : 0.f);
    else b = (oc < OC) ? bias1[oc] : 0.f;
    float v = (i & 1) ? acc[i >> 1].y : acc[i >> 1].x;
    y[i] = v + b;
  }
  if (wactive && pvalid) {
    float* outN = out + (size_t)outCH * (2 * (size_t)cPa[l]) +
                  (size_t)n * outCH * HW + (size_t)oy * W + ox;
#pragma unroll
    for (int i = 0; i < 16; ++i) {
      int oc = wsel + i;
      if (oc < OC) outN[(size_t)oc * HW] = y[i];
    }
  }
  if (GN_PART && wactive) {
#pragma unroll
    for (int gh = 0; gh < 2; ++gh) {
      double s = 0.0, ss = 0.0;
      if (pvalid) {
#pragma unroll
        for (int i = 8 * gh; i < 8 * gh + 8; ++i) {
          double d = (double)y[i];
          s += d; ss += d * d;
        }
      }
#pragma unroll
      for (int off = 1; off < 64; off <<= 1) {
        s += __shfl_xor(s, off, 64);
        ss += __shfl_xor(ss, off, 64);
      }
      if (lane == 0) {
        size_t slot = ((size_t)(cPTa[l] + tile) * 64 + n * 32 + (wsel >> 3) + gh);
        part[slot * 2] = s;
        part[slot * 2 + 1] = ss;
      }
    }
  }
}

// ---------------- GN coef from per-tile partials -----------------------------
__global__ __launch_bounds__(256) void k_coef(const double* __restrict__ part,
                                              const float* __restrict__ gs,
                                              const float* __restrict__ gb,
                                              float* __restrict__ cab) {
  int l = blockIdx.x >> 6, ng = blockIdx.x & 63, n = ng >> 5, g = ng & 31;
  int T = cTa[l];
  double s = 0.0, ss = 0.0;
  for (int tt = threadIdx.x; tt < T; tt += 256) {
    size_t slot = ((size_t)(cPTa[l] + tt) * 64 + ng);
    s += part[slot * 2];
    ss += part[slot * 2 + 1];
  }
  __shared__ double rs[256], rss[256];
  rs[threadIdx.x] = s; rss[threadIdx.x] = ss;
  __syncthreads();
  for (int off = 128; off > 0; off >>= 1) {
    if (threadIdx.x < off) {
      rs[threadIdx.x] += rs[threadIdx.x + off];
      rss[threadIdx.x] += rss[threadIdx.x + off];
    }
    __syncthreads();
  }
  if (threadIdx.x == 0) {
    int len = 8 * cHWa[l];
    double mu = rs[0] / len;
    double var = rss[0] / len - mu * mu;
    double rsq = 1.0 / sqrt(var + 1e-5);
    for (int cc = 0; cc < 8; ++cc) {
      int c = g * 8 + cc;
      double A = rsq * (double)gs[c];
      cab[((size_t)(l * 2 + n) * 256 + c) * 2] = (float)A;
      cab[((size_t)(l * 2 + n) * 256 + c) * 2 + 1] = (float)((double)gb[c] - mu * A);
    }
  }
}

// ---------------- decode scores: LG[l][n][81][HW] -> SF[(n*TOTHW+gi)*80+c] ---
__global__ void k_dscore(const float* __restrict__ LG, float* __restrict__ SF) {
  size_t i = (size_t)blockIdx.x * 256 + threadIdx.x;
  size_t tot = (size_t)2 * TOTHW * 80;
  if (i >= tot) return;
  int c = (int)(i % 80);
  size_t g = i / 80;
  int gi = (int)(g % TOTHW);
  int n = (int)(g / TOTHW);
  int l = lvl_of_pix(gi);
  int a = gi - cPa[l];
  int HW = cHWa[l];
  const float* base = LG + (size_t)162 * cPa[l] + (size_t)n * 81 * HW;
  float lg = base[(size_t)c * HW + a];
  float ct = base[(size_t)80 * HW + a];
  float s1 = 1.f / (1.f + expf(-lg));
  float s2 = 1.f / (1.f + expf(-ct));
  SF[i] = sqrtf(s1 * s2);
}

// ---------------- decode boxes -----------------------------------------------
__global__ void k_dbox(const float* __restrict__ RG, const float* __restrict__ scales,
                       float* __restrict__ BX) {
  int i = blockIdx.x * 256 + threadIdx.x;
  if (i >= 2 * TOTHW) return;
  int n = i / TOTHW, gi = i % TOTHW;
  int l = lvl_of_pix(gi);
  int a = gi - cPa[l];
  int HW = cHWa[l], W = cWa[l];
  const float* rg = RG + (size_t)8 * cPa[l] + (size_t)n * 4 * HW;
  float sc = scales[l];
  float stride = cSa[l];
  float r0 = fmaxf(0.f, sc * rg[a]);
  float r1 = fmaxf(0.f, sc * rg[HW + a]);
  float r2 = fmaxf(0.f, sc * rg[2 * HW + a]);
  float r3 = fmaxf(0.f, sc * rg[3 * HW + a]);
  int x = a % W, yv = a / W;
  float px = (x + 0.5f) * stride, py = (yv + 0.5f) * stride;
  float* bp = BX + (size_t)i * 4;
  bp[0] = px - r0 * stride; bp[1] = py - r1 * stride;
  bp[2] = px + r2 * stride; bp[3] = py + r3 * stride;
}

// ---------------- exact top-1000 per (n,level) -------------------------------
__global__ void k_hist1(const float* __restrict__ SF, unsigned* __restrict__ hist) {
  int nl = blockIdx.y; int n = nl & 1, l = nl >> 1;
  const float* s = SF + ((size_t)n * TOTHW + cPa[l]) * 80;
  int M = cHWa[l] * 80;
  unsigned* h = hist + nl * 1024;
  __shared__ unsigned lh[1024];
  for (int i = threadIdx.x; i < 1024; i += blockDim.x) lh[i] = 0;
  __syncthreads();
  for (int i = blockIdx.x * blockDim.x + threadIdx.x; i < M; i += gridDim.x * blockDim.x) {
    unsigned key = __float_as_uint(s[i]);
    unsigned b = key >> 20; if (b > 1023u) b = 1023u;
    atomicAdd(&lh[b], 1u);
  }
  __syncthreads();
  for (int i = threadIdx.x; i < 1024; i += blockDim.x)
    if (lh[i]) atomicAdd(&h[i], lh[i]);
}

__global__ void k_resolve1(const unsigned* __restrict__ hist, unsigned* __restrict__ ctl) {
  int nl = threadIdx.x;
  if (nl >= 10) return;
  const unsigned* h = hist + nl * 1024;
  unsigned acc = 0; int b = 1023;
  for (; b > 0; --b) { acc += h[b]; if (acc >= TOPKK) break; }
  if (acc < TOPKK) { acc += h[0]; b = 0; }
  ctl[nl] = (unsigned)b;
  ctl[10 + nl] = acc - h[b];
}

__global__ void k_hist2(const float* __restrict__ SF, const unsigned* __restrict__ ctl,
                        unsigned* __restrict__ hist2) {
  int nl = blockIdx.y; int n = nl & 1, l = nl >> 1;
  unsigned b1 = ctl[nl];
  const float* s = SF + ((size_t)n * TOTHW + cPa[l]) * 80;
  int M = cHWa[l] * 80;
  unsigned* h = hist2 + nl * 4096;
  __shared__ unsigned lh[4096];
  for (int i = threadIdx.x; i < 4096; i += blockDim.x) lh[i] = 0;
  __syncthreads();
  for (int i = blockIdx.x * blockDim.x + threadIdx.x; i < M; i += gridDim.x * blockDim.x) {
    unsigned key = __float_as_uint(s[i]);
    if ((key >> 20) == b1) atomicAdd(&lh[(key >> 8) & 0xFFFu], 1u);
  }
  __syncthreads();
  for (int i = threadIdx.x; i < 4096; i += blockDim.x)
    if (lh[i]) atomicAdd(&h[i], lh[i]);
}

__global__ void k_resolve2(const unsigned* __restrict__ hist2, unsigned* __restrict__ ctl) {
  int nl = threadIdx.x;
  if (nl >= 10) return;
  unsigned b1 = ctl[nl];
  unsigned acc = ctl[10 + nl];
  const unsigned* h = hist2 + nl * 4096;
  int b = 4095;
  for (; b > 0; --b) { acc += h[b]; if (acc >= TOPKK) break; }
  if (acc < TOPKK) b = 0;
  ctl[20 + nl] = (b1 << 12) | (unsigned)b;
}

__device__ __forceinline__ void write_cand(int n, int l, int pos, float v, int i,
                                           float* csc, float* ccl, int* gai) {
  int a = i / KCLS, c = i - a * KCLS;
  int g = n * NCAND + pos;
  csc[g] = (v > 0.05f) ? v : 0.f;
  ccl[g] = (float)c;
  gai[g] = cPa[l] + a;
}

__global__ void k_compact(const float* __restrict__ SF, const unsigned* __restrict__ ctl,
                          unsigned* __restrict__ cnt, float* __restrict__ eqV,
                          unsigned* __restrict__ eqI,
                          float* csc, float* ccl, int* gai) {
  int nl = blockIdx.y; int n = nl & 1, l = nl >> 1;
  const float* s = SF + ((size_t)n * TOTHW + cPa[l]) * 80;
  int M = cHWa[l] * 80;
  unsigned P = ctl[20 + nl];
  int loff = l * TOPKK;
  for (int i = blockIdx.x * blockDim.x + threadIdx.x; i < M; i += gridDim.x * blockDim.x) {
    float v = s[i];
    unsigned k24 = __float_as_uint(v) >> 8;
    if (k24 < P) continue;
    if (k24 > P) {
      unsigned slot = atomicAdd(&cnt[nl], 1u);
      write_cand(n, l, loff + (int)slot, v, i, csc, ccl, gai);
    } else {
      unsigned e = atomicAdd(&cnt[10 + nl], 1u);
      if (e < 2048u) { eqV[nl * 2048 + e] = v; eqI[nl * 2048 + e] = (unsigned)i; }
    }
  }
}

__global__ void k_eq(const float* __restrict__ eqV, const unsigned* __restrict__ eqI,
                     const unsigned* __restrict__ cnt,
                     float* csc, float* ccl, int* gai) {
  int nl = blockIdx.x; int n = nl & 1, l = nl >> 1;
  int above = (int)cnt[nl];
  unsigned ec = cnt[10 + nl];
  int E = ec < 2048u ? (int)ec : 2048;
  int r = TOPKK - above;
  int loff = l * TOPKK;
  for (int e = threadIdx.x; e < E; e += blockDim.x) {
    float v = eqV[nl * 2048 + e];
    unsigned idx = eqI[nl * 2048 + e];
    int rank = 0;
    for (int j = 0; j < E; ++j) {
      float vj = eqV[nl * 2048 + j];
      unsigned ij = eqI[nl * 2048 + j];
      if (vj > v || (vj == v && ij < idx)) rank++;
    }
    if (rank < r)
      write_cand(n, l, loff + above + rank, v, (int)idx, csc, ccl, gai);
  }
}

// ---------------- gather candidate boxes -------------------------------------
__global__ void k_gather(const int* __restrict__ gai, const float* __restrict__ ccl,
                         const float* __restrict__ BX,
                         float* __restrict__ cbx, float* __restrict__ cob) {
  int i = blockIdx.x * 256 + threadIdx.x;
  if (i >= 2 * NCAND) return;
  int n = i / NCAND;
  int a = gai[i];
  if (a < 0 || a >= TOTHW) a = 0;
  const float* bp = BX + ((size_t)n * TOTHW + a) * 4;
  float b0 = bp[0], b1 = bp[1], b2 = bp[2], b3 = bp[3];
  float off = ccl[i] * 1e4f;
  cbx[(size_t)i * 4 + 0] = b0; cbx[(size_t)i * 4 + 1] = b1;
  cbx[(size_t)i * 4 + 2] = b2; cbx[(size_t)i * 4 + 3] = b3;
  cob[(size_t)i * 4 + 0] = b0 + off; cob[(size_t)i * 4 + 1] = b1 + off;
  cob[(size_t)i * 4 + 2] = b2 + off; cob[(size_t)i * 4 + 3] = b3 + off;
}

// ---------------- NMS --------------------------------------------------------
__global__ __launch_bounds__(256) void k_nms(
    const float* __restrict__ cbox, const float* __restrict__ cobx,
    const float* __restrict__ cscore, const float* __restrict__ ccls,
    float* __restrict__ out) {
  int n = blockIdx.x;
  __shared__ float s[NCAND];
  __shared__ float area[NCAND];
  __shared__ float redV[4];
  __shared__ int redI[4];
  __shared__ float curV;
  __shared__ int curI;
  const float4* ob4 = (const float4*)(cobx + (size_t)n * NCAND * 4);
  for (int j = threadIdx.x; j < NCAND; j += 256) {
    s[j] = cscore[n * NCAND + j];
    float4 b = ob4[j];
    area[j] = fmaxf(b.z - b.x, 0.f) * fmaxf(b.w - b.y, 0.f);
  }
  __syncthreads();
  for (int it = 0; it < MAXDET; ++it) {
    float mv = -1.f; int mi = 0;
    for (int j = threadIdx.x; j < NCAND; j += 256) {
      float v = s[j];
      if (v > mv) { mv = v; mi = j; }
    }
    for (int off = 1; off < 64; off <<= 1) {
      float ov = __shfl_xor(mv, off);
      int oi = __shfl_xor(mi, off);
      if (ov > mv || (ov == mv && oi < mi)) { mv = ov; mi = oi; }
    }
    if ((threadIdx.x & 63) == 0) { redV[threadIdx.x >> 6] = mv; redI[threadIdx.x >> 6] = mi; }
    __syncthreads();
    if (threadIdx.x == 0) {
      float bv = redV[0]; int bi = redI[0];
      for (int w = 1; w < 4; ++w)
        if (redV[w] > bv || (redV[w] == bv && redI[w] < bi)) { bv = redV[w]; bi = redI[w]; }
      curV = bv; curI = bi;
    }
    __syncthreads();
    float si = curV; int i = curI;
    bool valid = si > 0.f;
    float4 bi4 = ob4[i];
    float ai = area[i];
    if (valid) {
      for (int j = threadIdx.x; j < NCAND; j += 256) {
        float4 bj = ob4[j];
        float iw = fmaxf(fminf(bi4.z, bj.z) - fmaxf(bi4.x, bj.x), 0.f);
        float ih = fmaxf(fminf(bi4.w, bj.w) - fmaxf(bi4.y, bj.y), 0.f);
        float inter = iw * ih;
        float iou = inter / fmaxf(ai + area[j] - inter, 1e-6f);
        if (iou > 0.6f || j == i) s[j] = 0.f;
      }
    }
    if (threadIdx.x == 0) {
      float* o = out + ((size_t)n * MAXDET + it) * 6;
      if (valid) {
        const float* bb = cbox + ((size_t)n * NCAND + i) * 4;
        o[0] = bb[0]; o[1] = bb[1]; o[2] = bb[2]; o[3] = bb[3];
        o[4] = si; o[5] = ccls[n * NCAND + i];
      } else {
        o[0] = o[1] = o[2] = o[3] = o[4] = o[5] = 0.f;
      }
    }
    __syncthreads();
  }
}

// ---------------- host orchestration -----------------------------------------
extern "C" void kernel_launch(void* const* d_in, const int* in_sizes, int n_in,
                              void* d_out, int out_size, void* d_ws, size_t ws_size,
                              hipStream_t stream) {
  FeatPtrs fp;
  for (int i = 0; i < 5; ++i) fp.p[i] = (const float*)d_in[i];
  const float* cls_w = (const float*)d_in[5];
  const float* cls_b = (const float*)d_in[6];
  const float* cls_gs = (const float*)d_in[7];
  const float* cls_gb = (const float*)d_in[8];
  const float* box_w = (const float*)d_in[9];
  const float* box_b = (const float*)d_in[10];
  const float* box_gs = (const float*)d_in[11];
  const float* box_gb = (const float*)d_in[12];
  const float* score_w = (const float*)d_in[13];
  const float* score_b = (const float*)d_in[14];
  const float* bbox_w = (const float*)d_in[15];
  const float* bbox_b = (const float*)d_in[16];
  const float* ctr_w = (const float*)d_in[17];
  const float* ctr_b = (const float*)d_in[18];
  const float* scales = (const float*)d_in[19];

  float* ws = (float*)d_ws;
  // workspace layout (floats)
  const size_t A_off    = 0;            // 10,376,704  (2*256*TOTHW)
  const size_t B_off    = 10376704;     // 10,376,704
  const size_t WT_off   = 20753408;     // 2,359,296   (tower weights, cls then box)
  const size_t WTS_off  = 23112704;     // 221,184     (score+ctr, OCpad 96)
  const size_t WTBB_off = 23333888;     // 36,864
  const size_t PART_off = 23370752;     // 88,320      (44160 doubles)
  const size_t CAB_off  = 23459072;     // 5,120
  const size_t CSC_off  = 23464192;     // 10,000
  const size_t CCL_off  = 23474192;     // 10,000
  const size_t GAI_off  = 23484192;     // 10,000
  const size_t H1_off   = 23494192;     // 10,240
  const size_t H2_off   = 23504432;     // 40,960
  const size_t CNT_off  = 23545392;     // 32
  const size_t CTL_off  = 23545424;     // 32
  const size_t EQV_off  = 23545456;     // 20,480
  const size_t EQI_off  = 23565936;     // 20,480
  // regions aliased inside A (A is dead/reusable at those points):
  const size_t LG_off  = A_off + 0;        // 3,283,254 (2*81*TOTHW)
  const size_t RG_off  = A_off + 4000000;  // 162,136
  const size_t BX_off  = A_off + 4200000;  // 162,136
  const size_t CBX_off = A_off + 4400000;  // 40,000
  const size_t COB_off = A_off + 4450000;  // 40,000
  const size_t SF_off  = A_off + 5000000;  // 3,242,720 (2*TOTHW*80)

  float* A = ws + A_off;
  float* B = ws + B_off;
  float* WT = ws + WT_off;
  float* WTS = ws + WTS_off;
  float* WTBB = ws + WTBB_off;
  double* PART = (double*)(ws + PART_off);
  float* CAB = ws + CAB_off;
  float* CSC = ws + CSC_off;
  float* CCL = ws + CCL_off;
  int* GAI = (int*)(ws + GAI_off);
  unsigned* H1 = (unsigned*)(ws + H1_off);
  unsigned* H2 = (unsigned*)(ws + H2_off);
  unsigned* CNT = (unsigned*)(ws + CNT_off);
  unsigned* CTL = (unsigned*)(ws + CTL_off);
  float* EQV = ws + EQV_off;
  unsigned* EQI = (unsigned*)(ws + EQI_off);
  float* LG = ws + LG_off;
  float* RG = ws + RG_off;
  float* BX = ws + BX_off;
  float* CBX = ws + CBX_off;
  float* COB = ws + COB_off;
  float* SF = ws + SF_off;

  // zero: padded head weights + candidate/hist/count region
  hipMemsetAsync(WTS, 0, (221184 + 36864) * sizeof(float), stream);
  hipMemsetAsync(CSC, 0, (CTL_off + 32 - CSC_off) * sizeof(float), stream);

  // repack cls tower + head weights
  for (int l = 0; l < 4; ++l)
    hipLaunchKernelGGL(k_repack, dim3(2304), dim3(256), 0, stream,
                       cls_w + (size_t)l * 256 * 2304, WT + (size_t)l * 589824, 256, 256, 0);
  hipLaunchKernelGGL(k_repack, dim3(720), dim3(256), 0, stream, score_w, WTS, 80, 96, 0);
  hipLaunchKernelGGL(k_repack, dim3(9), dim3(256), 0, stream, ctr_w, WTS, 1, 96, 80);
  hipLaunchKernelGGL(k_repack, dim3(36), dim3(256), 0, stream, bbox_w, WTBB, 4, 16, 0);

  dim3 gT(TT, 4, 2), gH(TT, 2, 2), gB1(TT, 1, 2), blk(256);

  // ---- cls tower: feats->A->B->A->B
  hipLaunchKernelGGL((k_conv<true, false, true, false>), gT, blk, 0, stream,
                     fp, (const float*)nullptr, WT, cls_b, (const float*)nullptr, CAB, A, 256, 256, 256, PART);
  hipLaunchKernelGGL(k_coef, dim3(320), blk, 0, stream, PART, cls_gs, cls_gb, CAB);
  hipLaunchKernelGGL((k_conv<false, true, true, false>), gT, blk, 0, stream,
                     fp, A, WT + 589824, cls_b + 256, (const float*)nullptr, CAB, B, 256, 256, 256, PART);
  hipLaunchKernelGGL(k_coef, dim3(320), blk, 0, stream, PART, cls_gs + 256, cls_gb + 256, CAB);
  hipLaunchKernelGGL((k_conv<false, true, true, false>), gT, blk, 0, stream,
                     fp, B, WT + 2 * 589824, cls_b + 512, (const float*)nullptr, CAB, A, 256, 256, 256, PART);
  hipLaunchKernelGGL(k_coef, dim3(320), blk, 0, stream, PART, cls_gs + 512, cls_gb + 512, CAB);
  hipLaunchKernelGGL((k_conv<false, true, true, false>), gT, blk, 0, stream,
                     fp, A, WT + 3 * 589824, cls_b + 768, (const float*)nullptr, CAB, B, 256, 256, 256, PART);
  hipLaunchKernelGGL(k_coef, dim3(320), blk, 0, stream, PART, cls_gs + 768, cls_gb + 768, CAB);

  // ---- score+ctr head: B -> LG (inside A; A's activations are dead)
  hipLaunchKernelGGL((k_conv<false, true, false, true>), gH, blk, 0, stream,
                     fp, B, WTS, score_b, ctr_b, CAB, LG, 81, 81, 96, PART);

  // ---- scores + top-1000 per (n,level)
  hipLaunchKernelGGL(k_dscore, dim3(12667), blk, 0, stream, LG, SF);
  hipLaunchKernelGGL(k_hist1, dim3(128, 10), blk, 0, stream, SF, H1);
  hipLaunchKernelGGL(k_resolve1, dim3(1), dim3(64), 0, stream, H1, CTL);
  hipLaunchKernelGGL(k_hist2, dim3(128, 10), blk, 0, stream, SF, CTL, H2);
  hipLaunchKernelGGL(k_resolve2, dim3(1), dim3(64), 0, stream, H2, CTL);
  hipLaunchKernelGGL(k_compact, dim3(128, 10), blk, 0, stream, SF, CTL, CNT, EQV, EQI, CSC, CCL, GAI);
  hipLaunchKernelGGL(k_eq, dim3(10), blk, 0, stream, EQV, EQI, CNT, CSC, CCL, GAI);

  // ---- repack box tower weights into WT (cls weights dead now)
  for (int l = 0; l < 4; ++l)
    hipLaunchKernelGGL(k_repack, dim3(2304), dim3(256), 0, stream,
                       box_w + (size_t)l * 256 * 2304, WT + (size_t)l * 589824, 256, 256, 0);

  // ---- box tower: feats->A->B->A->B (LG/SF consumed above)
  hipLaunchKernelGGL((k_conv<true, false, true, false>), gT, blk, 0, stream,
                     fp, (const float*)nullptr, WT, box_b, (const float*)nullptr, CAB, A, 256, 256, 256, PART);
  hipLaunchKernelGGL(k_coef, dim3(320), blk, 0, stream, PART, box_gs, box_gb, CAB);
  hipLaunchKernelGGL((k_conv<false, true, true, false>), gT, blk, 0, stream,
                     fp, A, WT + 589824, box_b + 256, (const float*)nullptr, CAB, B, 256, 256, 256, PART);
  hipLaunchKernelGGL(k_coef, dim3(320), blk, 0, stream, PART, box_gs + 256, box_gb + 256, CAB);
  hipLaunchKernelGGL((k_conv<false, true, true, false>), gT, blk, 0, stream,
                     fp, B, WT + 2 * 589824, box_b + 512, (const float*)nullptr, CAB, A, 256, 256, 256, PART);
  hipLaunchKernelGGL(k_coef, dim3(320), blk, 0, stream, PART, box_gs + 512, box_gb + 512, CAB);
  hipLaunchKernelGGL((k_conv<false, true, true, false>), gT, blk, 0, stream,
                     fp, A, WT + 3 * 589824, box_b + 768, (const float*)nullptr, CAB, B, 256, 256, 256, PART);
  hipLaunchKernelGGL(k_coef, dim3(320), blk, 0, stream, PART, box_gs + 768, box_gb + 768, CAB);

  // ---- bbox head: B -> RG (inside A)
  hipLaunchKernelGGL((k_conv<false, true, false, false>), gB1, blk, 0, stream,
                     fp, B, WTBB, bbox_b, (const float*)nullptr, CAB, RG, 4, 4, 16, PART);

  // ---- boxes, gather, NMS
  hipLaunchKernelGGL(k_dbox, dim3(159), blk, 0, stream, RG, scales, BX);
  hipLaunchKernelGGL(k_gather, dim3(40), blk, 0, stream, GAI, CCL, BX, CBX, COB);
  hipLaunchKernelGGL(k_nms, dim3(2), blk, 0, stream, CBX, COB, CSC, CCL, (float*)d_out);
}

// Round 4
// 2303.417 us; speedup vs baseline: 8.3564x; 2.9728x over previous
//
#include <hip/hip_runtime.h>
#include <math.h>

// FCOS RPN head, R4: split-f16 MFMA conv (Ootomo 2-term, 3 mfma/product,
// scaled x*32 / w*2048 to keep residuals f16-normal, de-scale 1/65536).
// Activations in [n][px][256] layout; A staged in LDS (XOR-swizzled,
// conflict-free b128 frags); B pre-repacked to per-lane 16B fragments in
// global. Per-wave 64px x 64oc (16 tiles). GN partials fused (fp64).
// Decode / exact top-1000 / NMS unchanged from R3 (passed, absmax 0.0).

#define KCLS 80
#define TOPKK 1000
#define NCAND 5000
#define MAXDET 100
#define TOTHW 20267

constexpr int cHa[5]  = {100, 50, 25, 13, 7};
constexpr int cWa[5]  = {152, 76, 38, 19, 10};
constexpr int cHWa[5] = {15200, 3800, 950, 247, 70};
constexpr int cPa[5]  = {0, 15200, 19000, 19950, 20197};
constexpr int cTXa[5] = {19, 10, 5, 3, 2};
constexpr int cPTa[5] = {0, 247, 317, 337, 343};
constexpr int cTa[5]  = {247, 70, 20, 6, 2};
constexpr float cSa[5] = {8.f, 16.f, 32.f, 64.f, 128.f};
constexpr int cPCh[5] = {0, 238, 298, 313, 317};  // 64-px transpose chunks

typedef _Float16 h8 __attribute__((ext_vector_type(8)));
typedef float f4 __attribute__((ext_vector_type(4)));

struct FeatPtrs { const float* p[5]; };

__device__ __forceinline__ int lvl_of_tile(int bx) {
  return (bx < 247) ? 0 : (bx < 317) ? 1 : (bx < 337) ? 2 : (bx < 343) ? 3 : 4;
}
__device__ __forceinline__ int lvl_of_pix(int gi) {
  return (gi < 15200) ? 0 : (gi < 19000) ? 1 : (gi < 19950) ? 2 : (gi < 20197) ? 3 : 4;
}

// ---------------- feats transpose: [c][H][W] -> FT[n][gi][256] --------------
__global__ __launch_bounds__(256) void k_tf(FeatPtrs fp, float* __restrict__ FT) {
  int b = blockIdx.x, n = blockIdx.y;
  int l = (b < 238) ? 0 : (b < 298) ? 1 : (b < 313) ? 2 : (b < 317) ? 3 : 4;
  int ch = b - cPCh[l];
  int HW = cHWa[l];
  int px0 = ch * 64;
  const float* src = fp.p[l] + (size_t)n * 256 * HW;
  __shared__ float tile[64][65];
  int tid = threadIdx.x;
  int a0 = tid & 63, a1 = tid >> 6;
  for (int icc = 0; icc < 256; icc += 64) {
    __syncthreads();
#pragma unroll
    for (int j = 0; j < 16; ++j) {
      int ic = icc + a1 * 16 + j;
      int px = px0 + a0;
      tile[a0][a1 * 16 + j] = (px < HW) ? src[(size_t)ic * HW + px] : 0.f;
    }
    __syncthreads();
#pragma unroll
    for (int j = 0; j < 16; ++j) {
      int pxl = a1 * 16 + j;
      int px = px0 + pxl;
      if (px < HW)
        FT[((size_t)(n * TOTHW + cPa[l] + px)) * 256 + icc + a0] = tile[pxl][a0];
    }
  }
}

// ---------------- weight repack to MFMA B-fragment order, f16 split ----------
// Wf elem i -> j=i&7, kh=(i>>3)&3, c=(i>>5)&15, rest=i>>9: g = rest%G, ti=rest/G
// ics=ti&7, t=ti>>3 ; oc=g*16+c ; ic=ics*32+kh*8+j ; value = w[oc][ic][t]*2048
__global__ void k_rep(const float* __restrict__ w, const float* __restrict__ w2,
                      _Float16* __restrict__ Wh, _Float16* __restrict__ Wl,
                      int OC, int OCpad) {
  int i = blockIdx.x * 256 + threadIdx.x;
  int tot = 2304 * OCpad;
  if (i >= tot) return;
  int j = i & 7, kh = (i >> 3) & 3, c = (i >> 5) & 15;
  int rest = i >> 9;
  int G = OCpad >> 4;
  int g = rest % G, ti = rest / G;
  int ics = ti & 7, t = ti >> 3;
  int oc = g * 16 + c, ic = ics * 32 + kh * 8 + j;
  float v = 0.f;
  if (oc < OC) v = w[((size_t)oc * 256 + ic) * 9 + t];
  else if (w2 != nullptr && oc == OC) v = w2[(size_t)ic * 9 + t];
  float sv = v * 2048.f;
  _Float16 h = (_Float16)sv;
  Wh[i] = h;
  Wl[i] = (_Float16)(sv - (float)h);
}

// ---------------- MFMA conv3x3 pad=1 Cin=256, all levels batched -------------
// block 256thr = 4 waves; 8x8 spatial tile (64px); wave -> NT*16 ocs, 4 M-tiles.
template<bool AFFINE, bool GN_PART, bool HEAD, int NT>
__global__ __launch_bounds__(256) void k_cmf(
    const float* __restrict__ actIn,
    const _Float16* __restrict__ Wh, const _Float16* __restrict__ Wl,
    const float* __restrict__ bias1, const float* __restrict__ bias2,
    const float* __restrict__ cab, float* __restrict__ out,
    int outCH, int OC, double* __restrict__ part) {
  const int bx = blockIdx.x;
  const int lvl = lvl_of_tile(bx);
  const int tile = bx - cPTa[lvl];
  const int H = cHa[lvl], W = cWa[lvl];
  const int tx0 = (tile % cTXa[lvl]) * 8, ty0 = (tile / cTXa[lvl]) * 8;
  const int n = blockIdx.z;
  const int t = threadIdx.x, wv = t >> 6, lane = t & 63;
  const int kh = lane >> 4, c = lane & 15;

  __shared__ _Float16 sH[6400];
  __shared__ _Float16 sL[6400];

  const float* cabL = cab + (size_t)(lvl * 2 + n) * 512;

  // staging slots: 800 = 100 halo px * 8 ic-groups(8)
  const float* sp[4];
  int shp[4], sgp[4];
  bool sinb[4], shas[4];
#pragma unroll
  for (int s = 0; s < 4; ++s) {
    int e = t + 256 * s;
    bool has = e < 800;
    int grp = e & 7, hp = e >> 3;
    if (hp > 99) hp = 99;
    int yy = hp / 10, xx = hp % 10;
    int gy = ty0 + yy - 1, gx = tx0 + xx - 1;
    bool inb = has && ((unsigned)gy < (unsigned)H) && ((unsigned)gx < (unsigned)W);
    int gpx = inb ? (cPa[lvl] + gy * W + gx) : 0;
    sp[s] = actIn + ((size_t)(n * TOTHW + gpx)) * 256 + grp * 8;
    shp[s] = hp; sgp[s] = grp; sinb[s] = inb; shas[s] = has;
  }

  f4 acc[4][NT];
#pragma unroll
  for (int m = 0; m < 4; ++m)
#pragma unroll
    for (int nt = 0; nt < NT; ++nt) acc[m][nt] = (f4)(0.f);

  float4 fv[4][2];
#pragma unroll
  for (int s = 0; s < 4; ++s) {
    if (sinb[s]) {
      fv[s][0] = *(const float4*)(sp[s]);
      fv[s][1] = *(const float4*)(sp[s] + 4);
    } else {
      fv[s][0] = make_float4(0.f, 0.f, 0.f, 0.f);
      fv[s][1] = make_float4(0.f, 0.f, 0.f, 0.f);
    }
  }

  const int lB = (c * 4 + kh) * 8;  // lane's B-frag offset (f16 elems)

#pragma unroll 1
  for (int icc = 0; icc < 256; icc += 64) {
    __syncthreads();
#pragma unroll
    for (int s = 0; s < 4; ++s) {
      if (shas[s]) {
        float vv[8];
        vv[0] = fv[s][0].x; vv[1] = fv[s][0].y; vv[2] = fv[s][0].z; vv[3] = fv[s][0].w;
        vv[4] = fv[s][1].x; vv[5] = fv[s][1].y; vv[6] = fv[s][1].z; vv[7] = fv[s][1].w;
        if (AFFINE && sinb[s]) {
#pragma unroll
          for (int j = 0; j < 8; ++j) {
            int ch = icc + sgp[s] * 8 + j;
            vv[j] = fmaxf(0.f, fmaf(vv[j], cabL[2 * ch], cabL[2 * ch + 1]));
          }
        }
        h8 hv, lv2;
#pragma unroll
        for (int j = 0; j < 8; ++j) {
          float sv = vv[j] * 32.f;
          _Float16 hh = (_Float16)sv;
          hv[j] = hh;
          lv2[j] = (_Float16)(sv - (float)hh);
        }
        int boff = ((shp[s] << 7) + (sgp[s] << 4)) ^ ((shp[s] & 7) << 4);
        *(h8*)((char*)sH + boff) = hv;
        *(h8*)((char*)sL + boff) = lv2;
      }
    }
    if (icc < 192) {
#pragma unroll
      for (int s = 0; s < 4; ++s) {
        if (sinb[s]) {
          fv[s][0] = *(const float4*)(sp[s] + icc + 64);
          fv[s][1] = *(const float4*)(sp[s] + icc + 68);
        }
      }
    }
    __syncthreads();

#pragma unroll 1
    for (int dy = 0; dy < 3; ++dy) {
#pragma unroll 1
      for (int dx = 0; dx < 3; ++dx) {
        const int t9 = dy * 3 + dx;
#pragma unroll
        for (int ics = 0; ics < 2; ++ics) {
          const int ICS = (icc >> 5) + ics;
          size_t wb = ((size_t)(t9 * 8 + ICS) * (NT * 4) + wv * NT) * 512 + lB;
          h8 bh[NT], bl[NT];
#pragma unroll
          for (int nt = 0; nt < NT; ++nt) {
            bh[nt] = *(const h8*)(Wh + wb + nt * 512);
            bl[nt] = *(const h8*)(Wl + wb + nt * 512);
          }
#pragma unroll
          for (int m = 0; m < 4; ++m) {
            int pxA = m * 16 + c;
            int hpA = ((pxA >> 3) + dy) * 10 + (pxA & 7) + dx;
            int boffA = ((hpA << 7) + (ics << 6) + (kh << 4)) ^ ((hpA & 7) << 4);
            h8 Ah = *(const h8*)((const char*)sH + boffA);
            h8 Al = *(const h8*)((const char*)sL + boffA);
#pragma unroll
            for (int nt = 0; nt < NT; ++nt) {
              acc[m][nt] = __builtin_amdgcn_mfma_f32_16x16x32_f16(Ah, bh[nt], acc[m][nt], 0, 0, 0);
              acc[m][nt] = __builtin_amdgcn_mfma_f32_16x16x32_f16(Ah, bl[nt], acc[m][nt], 0, 0, 0);
              acc[m][nt] = __builtin_amdgcn_mfma_f32_16x16x32_f16(Al, bh[nt], acc[m][nt], 0, 0, 0);
            }
          }
        }
      }
    }
  }

  // epilogue: de-scale, bias, store [n][px][outCH], fused GN partials (fp64)
  const float inv = 1.f / 65536.f;
#pragma unroll
  for (int nt = 0; nt < NT; ++nt) {
    int oc = wv * (NT * 16) + nt * 16 + c;
    float bb;
    if (HEAD) bb = (oc < KCLS) ? bias1[oc] : (oc == KCLS ? bias2[0] : 0.f);
    else bb = (oc < OC) ? bias1[oc] : 0.f;
    double s = 0.0, ss = 0.0;
#pragma unroll
    for (int m = 0; m < 4; ++m) {
#pragma unroll
      for (int r = 0; r < 4; ++r) {
        int px = m * 16 + kh * 4 + r;
        int oy = ty0 + (px >> 3), ox = tx0 + (px & 7);
        bool vpx = (oy < H) && (ox < W);
        float y = fmaf(acc[m][nt][r], inv, bb);
        if (vpx && oc < OC)
          out[((size_t)(n * TOTHW + cPa[lvl] + oy * W + ox)) * outCH + oc] = y;
        if (GN_PART && vpx) { double d = (double)y; s += d; ss += d * d; }
      }
    }
    if (GN_PART) {
#pragma unroll
      for (int msk = 16; msk <= 32; msk <<= 1) {
        s += __shfl_xor(s, msk, 64);
        ss += __shfl_xor(ss, msk, 64);
      }
#pragma unroll
      for (int msk = 1; msk <= 4; msk <<= 1) {
        s += __shfl_xor(s, msk, 64);
        ss += __shfl_xor(ss, msk, 64);
      }
      if (lane == 0 || lane == 8) {
        int G = wv * 8 + nt * 2 + (lane >> 3);
        size_t sl = (((size_t)bx * 2 + n) * 32 + G) * 2;
        part[sl] = s;
        part[sl + 1] = ss;
      }
    }
  }
}

// ---------------- GN coef from per-tile partials -----------------------------
__global__ __launch_bounds__(256) void k_coef(const double* __restrict__ part,
                                              const float* __restrict__ gs,
                                              const float* __restrict__ gb,
                                              float* __restrict__ cab) {
  int l = blockIdx.x >> 6, ng = blockIdx.x & 63, n = ng >> 5, g = ng & 31;
  int T = cTa[l];
  double s = 0.0, ss = 0.0;
  for (int tt = threadIdx.x; tt < T; tt += 256) {
    size_t sl = (((size_t)(cPTa[l] + tt) * 2 + n) * 32 + g) * 2;
    s += part[sl]; ss += part[sl + 1];
  }
  __shared__ double rs[256], rss[256];
  rs[threadIdx.x] = s; rss[threadIdx.x] = ss;
  __syncthreads();
  for (int off = 128; off > 0; off >>= 1) {
    if (threadIdx.x < off) {
      rs[threadIdx.x] += rs[threadIdx.x + off];
      rss[threadIdx.x] += rss[threadIdx.x + off];
    }
    __syncthreads();
  }
  if (threadIdx.x == 0) {
    int len = 8 * cHWa[l];
    double mu = rs[0] / len;
    double var = rss[0] / len - mu * mu;
    double rsq = 1.0 / sqrt(var + 1e-5);
    for (int cc = 0; cc < 8; ++cc) {
      int ch = g * 8 + cc;
      double A = rsq * (double)gs[ch];
      cab[((size_t)(l * 2 + n) * 256 + ch) * 2] = (float)A;
      cab[((size_t)(l * 2 + n) * 256 + ch) * 2 + 1] = (float)((double)gb[ch] - mu * A);
    }
  }
}

// ---------------- decode scores: LG[n][gi][96] -> SF[(n*TOTHW+gi)*80+c] ------
__global__ void k_dscore(const float* __restrict__ LG, float* __restrict__ SF) {
  size_t i = (size_t)blockIdx.x * 256 + threadIdx.x;
  size_t tot = (size_t)2 * TOTHW * 80;
  if (i >= tot) return;
  int c = (int)(i % 80);
  size_t g = i / 80;
  const float* base = LG + g * 96;
  float lg = base[c];
  float ct = base[80];
  float s1 = 1.f / (1.f + expf(-lg));
  float s2 = 1.f / (1.f + expf(-ct));
  SF[i] = sqrtf(s1 * s2);
}

// ---------------- decode boxes: RG[n][gi][8] -> BX ---------------------------
__global__ void k_dbox(const float* __restrict__ RG, const float* __restrict__ scales,
                       float* __restrict__ BX) {
  int i = blockIdx.x * 256 + threadIdx.x;
  if (i >= 2 * TOTHW) return;
  int gi = i % TOTHW;
  int l = lvl_of_pix(gi);
  int a = gi - cPa[l];
  int W = cWa[l];
  const float* rg = RG + (size_t)i * 8;
  float sc = scales[l];
  float stride = cSa[l];
  float r0 = fmaxf(0.f, sc * rg[0]);
  float r1 = fmaxf(0.f, sc * rg[1]);
  float r2 = fmaxf(0.f, sc * rg[2]);
  float r3 = fmaxf(0.f, sc * rg[3]);
  int x = a % W, yv = a / W;
  float px = (x + 0.5f) * stride, py = (yv + 0.5f) * stride;
  float* bp = BX + (size_t)i * 4;
  bp[0] = px - r0 * stride; bp[1] = py - r1 * stride;
  bp[2] = px + r2 * stride; bp[3] = py + r3 * stride;
}

// ---------------- exact top-1000 per (n,level) -------------------------------
__global__ void k_hist1(const float* __restrict__ SF, unsigned* __restrict__ hist) {
  int nl = blockIdx.y; int n = nl & 1, l = nl >> 1;
  const float* s = SF + ((size_t)n * TOTHW + cPa[l]) * 80;
  int M = cHWa[l] * 80;
  unsigned* h = hist + nl * 1024;
  __shared__ unsigned lh[1024];
  for (int i = threadIdx.x; i < 1024; i += blockDim.x) lh[i] = 0;
  __syncthreads();
  for (int i = blockIdx.x * blockDim.x + threadIdx.x; i < M; i += gridDim.x * blockDim.x) {
    unsigned key = __float_as_uint(s[i]);
    unsigned b = key >> 20; if (b > 1023u) b = 1023u;
    atomicAdd(&lh[b], 1u);
  }
  __syncthreads();
  for (int i = threadIdx.x; i < 1024; i += blockDim.x)
    if (lh[i]) atomicAdd(&h[i], lh[i]);
}

__global__ void k_resolve1(const unsigned* __restrict__ hist, unsigned* __restrict__ ctl) {
  int nl = threadIdx.x;
  if (nl >= 10) return;
  const unsigned* h = hist + nl * 1024;
  unsigned acc = 0; int b = 1023;
  for (; b > 0; --b) { acc += h[b]; if (acc >= TOPKK) break; }
  if (acc < TOPKK) { acc += h[0]; b = 0; }
  ctl[nl] = (unsigned)b;
  ctl[10 + nl] = acc - h[b];
}

__global__ void k_hist2(const float* __restrict__ SF, const unsigned* __restrict__ ctl,
                        unsigned* __restrict__ hist2) {
  int nl = blockIdx.y; int n = nl & 1, l = nl >> 1;
  unsigned b1 = ctl[nl];
  const float* s = SF + ((size_t)n * TOTHW + cPa[l]) * 80;
  int M = cHWa[l] * 80;
  unsigned* h = hist2 + nl * 4096;
  __shared__ unsigned lh[4096];
  for (int i = threadIdx.x; i < 4096; i += blockDim.x) lh[i] = 0;
  __syncthreads();
  for (int i = blockIdx.x * blockDim.x + threadIdx.x; i < M; i += gridDim.x * blockDim.x) {
    unsigned key = __float_as_uint(s[i]);
    if ((key >> 20) == b1) atomicAdd(&lh[(key >> 8) & 0xFFFu], 1u);
  }
  __syncthreads();
  for (int i = threadIdx.x; i < 4096; i += blockDim.x)
    if (lh[i]) atomicAdd(&h[i], lh[i]);
}

__global__ void k_resolve2(const unsigned* __restrict__ hist2, unsigned* __restrict__ ctl) {
  int nl = threadIdx.x;
  if (nl >= 10) return;
  unsigned b1 = ctl[nl];
  unsigned acc = ctl[10 + nl];
  const unsigned* h = hist2 + nl * 4096;
  int b = 4095;
  for (; b > 0; --b) { acc += h[b]; if (acc >= TOPKK) break; }
  if (acc < TOPKK) b = 0;
  ctl[20 + nl] = (b1 << 12) | (unsigned)b;
}

__device__ __forceinline__ void write_cand(int n, int l, int pos, float v, int i,
                                           float* csc, float* ccl, int* gai) {
  int a = i / KCLS, c = i - a * KCLS;
  int g = n * NCAND + pos;
  csc[g] = (v > 0.05f) ? v : 0.f;
  ccl[g] = (float)c;
  gai[g] = cPa[l] + a;
}

__global__ void k_compact(const float* __restrict__ SF, const unsigned* __restrict__ ctl,
                          unsigned* __restrict__ cnt, float* __restrict__ eqV,
                          unsigned* __restrict__ eqI,
                          float* csc, float* ccl, int* gai) {
  int nl = blockIdx.y; int n = nl & 1, l = nl >> 1;
  const float* s = SF + ((size_t)n * TOTHW + cPa[l]) * 80;
  int M = cHWa[l] * 80;
  unsigned P = ctl[20 + nl];
  int loff = l * TOPKK;
  for (int i = blockIdx.x * blockDim.x + threadIdx.x; i < M; i += gridDim.x * blockDim.x) {
    float v = s[i];
    unsigned k24 = __float_as_uint(v) >> 8;
    if (k24 < P) continue;
    if (k24 > P) {
      unsigned slot = atomicAdd(&cnt[nl], 1u);
      write_cand(n, l, loff + (int)slot, v, i, csc, ccl, gai);
    } else {
      unsigned e = atomicAdd(&cnt[10 + nl], 1u);
      if (e < 2048u) { eqV[nl * 2048 + e] = v; eqI[nl * 2048 + e] = (unsigned)i; }
    }
  }
}

__global__ void k_eq(const float* __restrict__ eqV, const unsigned* __restrict__ eqI,
                     const unsigned* __restrict__ cnt,
                     float* csc, float* ccl, int* gai) {
  int nl = blockIdx.x; int n = nl & 1, l = nl >> 1;
  int above = (int)cnt[nl];
  unsigned ec = cnt[10 + nl];
  int E = ec < 2048u ? (int)ec : 2048;
  int r = TOPKK - above;
  int loff = l * TOPKK;
  for (int e = threadIdx.x; e < E; e += blockDim.x) {
    float v = eqV[nl * 2048 + e];
    unsigned idx = eqI[nl * 2048 + e];
    int rank = 0;
    for (int j = 0; j < E; ++j) {
      float vj = eqV[nl * 2048 + j];
      unsigned ij = eqI[nl * 2048 + j];
      if (vj > v || (vj == v && ij < idx)) rank++;
    }
    if (rank < r)
      write_cand(n, l, loff + above + rank, v, (int)idx, csc, ccl, gai);
  }
}

// ---------------- gather candidate boxes -------------------------------------
__global__ void k_gather(const int* __restrict__ gai, const float* __restrict__ ccl,
                         const float* __restrict__ BX,
                         float* __restrict__ cbx, float* __restrict__ cob) {
  int i = blockIdx.x * 256 + threadIdx.x;
  if (i >= 2 * NCAND) return;
  int n = i / NCAND;
  int a = gai[i];
  if (a < 0 || a >= TOTHW) a = 0;
  const float* bp = BX + ((size_t)n * TOTHW + a) * 4;
  float b0 = bp[0], b1 = bp[1], b2 = bp[2], b3 = bp[3];
  float off = ccl[i] * 1e4f;
  cbx[(size_t)i * 4 + 0] = b0; cbx[(size_t)i * 4 + 1] = b1;
  cbx[(size_t)i * 4 + 2] = b2; cbx[(size_t)i * 4 + 3] = b3;
  cob[(size_t)i * 4 + 0] = b0 + off; cob[(size_t)i * 4 + 1] = b1 + off;
  cob[(size_t)i * 4 + 2] = b2 + off; cob[(size_t)i * 4 + 3] = b3 + off;
}

// ---------------- NMS --------------------------------------------------------
__global__ __launch_bounds__(256) void k_nms(
    const float* __restrict__ cbox, const float* __restrict__ cobx,
    const float* __restrict__ cscore, const float* __restrict__ ccls,
    float* __restrict__ out) {
  int n = blockIdx.x;
  __shared__ float s[NCAND];
  __shared__ float area[NCAND];
  __shared__ float redV[4];
  __shared__ int redI[4];
  __shared__ float curV;
  __shared__ int curI;
  const float4* ob4 = (const float4*)(cobx + (size_t)n * NCAND * 4);
  for (int j = threadIdx.x; j < NCAND; j += 256) {
    s[j] = cscore[n * NCAND + j];
    float4 b = ob4[j];
    area[j] = fmaxf(b.z - b.x, 0.f) * fmaxf(b.w - b.y, 0.f);
  }
  __syncthreads();
  for (int it = 0; it < MAXDET; ++it) {
    float mv = -1.f; int mi = 0;
    for (int j = threadIdx.x; j < NCAND; j += 256) {
      float v = s[j];
      if (v > mv) { mv = v; mi = j; }
    }
    for (int off = 1; off < 64; off <<= 1) {
      float ov = __shfl_xor(mv, off);
      int oi = __shfl_xor(mi, off);
      if (ov > mv || (ov == mv && oi < mi)) { mv = ov; mi = oi; }
    }
    if ((threadIdx.x & 63) == 0) { redV[threadIdx.x >> 6] = mv; redI[threadIdx.x >> 6] = mi; }
    __syncthreads();
    if (threadIdx.x == 0) {
      float bv = redV[0]; int bi = redI[0];
      for (int w = 1; w < 4; ++w)
        if (redV[w] > bv || (redV[w] == bv && redI[w] < bi)) { bv = redV[w]; bi = redI[w]; }
      curV = bv; curI = bi;
    }
    __syncthreads();
    float si = curV; int i = curI;
    bool valid = si > 0.f;
    float4 bi4 = ob4[i];
    float ai = area[i];
    if (valid) {
      for (int j = threadIdx.x; j < NCAND; j += 256) {
        float4 bj = ob4[j];
        float iw = fmaxf(fminf(bi4.z, bj.z) - fmaxf(bi4.x, bj.x), 0.f);
        float ih = fmaxf(fminf(bi4.w, bj.w) - fmaxf(bi4.y, bj.y), 0.f);
        float inter = iw * ih;
        float iou = inter / fmaxf(ai + area[j] - inter, 1e-6f);
        if (iou > 0.6f || j == i) s[j] = 0.f;
      }
    }
    if (threadIdx.x == 0) {
      float* o = out + ((size_t)n * MAXDET + it) * 6;
      if (valid) {
        const float* bb = cbox + ((size_t)n * NCAND + i) * 4;
        o[0] = bb[0]; o[1] = bb[1]; o[2] = bb[2]; o[3] = bb[3];
        o[4] = si; o[5] = ccls[n * NCAND + i];
      } else {
        o[0] = o[1] = o[2] = o[3] = o[4] = o[5] = 0.f;
      }
    }
    __syncthreads();
  }
}

// ---------------- host orchestration -----------------------------------------
extern "C" void kernel_launch(void* const* d_in, const int* in_sizes, int n_in,
                              void* d_out, int out_size, void* d_ws, size_t ws_size,
                              hipStream_t stream) {
  FeatPtrs fp;
  for (int i = 0; i < 5; ++i) fp.p[i] = (const float*)d_in[i];
  const float* cls_w = (const float*)d_in[5];
  const float* cls_b = (const float*)d_in[6];
  const float* cls_gs = (const float*)d_in[7];
  const float* cls_gb = (const float*)d_in[8];
  const float* box_w = (const float*)d_in[9];
  const float* box_b = (const float*)d_in[10];
  const float* box_gs = (const float*)d_in[11];
  const float* box_gb = (const float*)d_in[12];
  const float* score_w = (const float*)d_in[13];
  const float* score_b = (const float*)d_in[14];
  const float* bbox_w = (const float*)d_in[15];
  const float* bbox_b = (const float*)d_in[16];
  const float* ctr_w = (const float*)d_in[17];
  const float* ctr_b = (const float*)d_in[18];
  const float* scales = (const float*)d_in[19];

  float* ws = (float*)d_ws;
  const size_t A_off    = 0;           // 10,376,704
  const size_t B_off    = 10376704;    // 10,376,704 (also feats-transpose FT)
  const size_t WTh_off  = 20753408;    // 1,179,648 (4 layers x 294,912)
  const size_t WTl_off  = 21933056;    // 1,179,648
  const size_t WSh_off  = 23112704;    // 147,456
  const size_t WSl_off  = 23260160;    // 147,456
  const size_t WBh_off  = 23407616;    // 73,728
  const size_t WBl_off  = 23481344;    // 73,728
  const size_t PART_off = 23555072;    // 176,640 (88,320 doubles)
  const size_t CAB_off  = 23731712;    // 5,120
  const size_t CSC_off  = 23736832;    // 10,000
  const size_t CCL_off  = 23746832;    // 10,000
  const size_t GAI_off  = 23756832;    // 10,000
  const size_t H1_off   = 23766832;    // 10,240
  const size_t H2_off   = 23777072;    // 40,960
  const size_t CNT_off  = 23818032;    // 32
  const size_t CTL_off  = 23818064;    // 32
  const size_t EQV_off  = 23818096;    // 20,480
  const size_t EQI_off  = 23838576;    // 20,480
  // aliases inside A (dead at time of use; see flow):
  const size_t LG_off   = A_off + 0;        // 2*TOTHW*96 = 3,891,264
  const size_t SF_off   = A_off + 4000000;  // 3,242,720
  const size_t RG_off   = A_off + 7300000;  // 2*TOTHW*8 = 324,272
  const size_t BX_off   = A_off + 7700000;  // 162,136
  const size_t CBX_off  = A_off + 7900000;  // 40,000
  const size_t COB_off  = A_off + 7950000;  // 40,000

  float* A = ws + A_off;
  float* B = ws + B_off;
  _Float16* WTh = (_Float16*)(ws + WTh_off);
  _Float16* WTl = (_Float16*)(ws + WTl_off);
  _Float16* WSh = (_Float16*)(ws + WSh_off);
  _Float16* WSl = (_Float16*)(ws + WSl_off);
  _Float16* WBh = (_Float16*)(ws + WBh_off);
  _Float16* WBl = (_Float16*)(ws + WBl_off);
  double* PART = (double*)(ws + PART_off);
  float* CAB = ws + CAB_off;
  float* CSC = ws + CSC_off;
  float* CCL = ws + CCL_off;
  int* GAI = (int*)(ws + GAI_off);
  unsigned* H1 = (unsigned*)(ws + H1_off);
  unsigned* H2 = (unsigned*)(ws + H2_off);
  unsigned* CNT = (unsigned*)(ws + CNT_off);
  unsigned* CTL = (unsigned*)(ws + CTL_off);
  float* EQV = ws + EQV_off;
  unsigned* EQI = (unsigned*)(ws + EQI_off);
  float* LG = ws + LG_off;
  float* SF = ws + SF_off;
  float* RG = ws + RG_off;
  float* BX = ws + BX_off;
  float* CBX = ws + CBX_off;
  float* COB = ws + COB_off;

  // zero hist/count/candidate region
  hipMemsetAsync(CSC, 0, (CTL_off + 32 - CSC_off) * sizeof(float), stream);

  dim3 blk(256);
  // repack cls tower + heads
  for (int ll = 0; ll < 4; ++ll)
    hipLaunchKernelGGL(k_rep, dim3(2304), blk, 0, stream,
                       cls_w + (size_t)ll * 589824, (const float*)nullptr,
                       WTh + (size_t)ll * 589824, WTl + (size_t)ll * 589824, 256, 256);
  hipLaunchKernelGGL(k_rep, dim3(1152), blk, 0, stream, score_w, ctr_w, WSh, WSl, 80, 128);
  hipLaunchKernelGGL(k_rep, dim3(576), blk, 0, stream, bbox_w, (const float*)nullptr,
                     WBh, WBl, 4, 64);

  // transpose feats -> B
  hipLaunchKernelGGL(k_tf, dim3(319, 2), blk, 0, stream, fp, B);

  dim3 gC(345, 1, 2);
  // ---- cls tower: B(FT)->A->B->A->B
  hipLaunchKernelGGL((k_cmf<false, true, false, 4>), gC, blk, 0, stream,
                     B, WTh, WTl, cls_b, (const float*)nullptr, CAB, A, 256, 256, PART);
  hipLaunchKernelGGL(k_coef, dim3(320), blk, 0, stream, PART, cls_gs, cls_gb, CAB);
  hipLaunchKernelGGL((k_cmf<true, true, false, 4>), gC, blk, 0, stream,
                     A, WTh + 589824, WTl + 589824, cls_b + 256, (const float*)nullptr, CAB, B, 256, 256, PART);
  hipLaunchKernelGGL(k_coef, dim3(320), blk, 0, stream, PART, cls_gs + 256, cls_gb + 256, CAB);
  hipLaunchKernelGGL((k_cmf<true, true, false, 4>), gC, blk, 0, stream,
                     B, WTh + 2 * 589824, WTl + 2 * 589824, cls_b + 512, (const float*)nullptr, CAB, A, 256, 256, PART);
  hipLaunchKernelGGL(k_coef, dim3(320), blk, 0, stream, PART, cls_gs + 512, cls_gb + 512, CAB);
  hipLaunchKernelGGL((k_cmf<true, true, false, 4>), gC, blk, 0, stream,
                     A, WTh + 3 * 589824, WTl + 3 * 589824, cls_b + 768, (const float*)nullptr, CAB, B, 256, 256, PART);
  hipLaunchKernelGGL(k_coef, dim3(320), blk, 0, stream, PART, cls_gs + 768, cls_gb + 768, CAB);

  // ---- score+ctr head: B -> LG (in A)
  hipLaunchKernelGGL((k_cmf<true, false, true, 2>), gC, blk, 0, stream,
                     B, WSh, WSl, score_b, ctr_b, CAB, LG, 96, 81, (double*)nullptr);

  // ---- scores + exact top-1000
  hipLaunchKernelGGL(k_dscore, dim3(12667), blk, 0, stream, LG, SF);
  hipLaunchKernelGGL(k_hist1, dim3(128, 10), blk, 0, stream, SF, H1);
  hipLaunchKernelGGL(k_resolve1, dim3(1), dim3(64), 0, stream, H1, CTL);
  hipLaunchKernelGGL(k_hist2, dim3(128, 10), blk, 0, stream, SF, CTL, H2);
  hipLaunchKernelGGL(k_resolve2, dim3(1), dim3(64), 0, stream, H2, CTL);
  hipLaunchKernelGGL(k_compact, dim3(128, 10), blk, 0, stream, SF, CTL, CNT, EQV, EQI, CSC, CCL, GAI);
  hipLaunchKernelGGL(k_eq, dim3(10), blk, 0, stream, EQV, EQI, CNT, CSC, CCL, GAI);

  // ---- repack box tower into WT (cls weights dead), re-transpose feats -> B
  for (int ll = 0; ll < 4; ++ll)
    hipLaunchKernelGGL(k_rep, dim3(2304), blk, 0, stream,
                       box_w + (size_t)ll * 589824, (const float*)nullptr,
                       WTh + (size_t)ll * 589824, WTl + (size_t)ll * 589824, 256, 256);
  hipLaunchKernelGGL(k_tf, dim3(319, 2), blk, 0, stream, fp, B);

  // ---- box tower: B(FT)->A->B->A->B
  hipLaunchKernelGGL((k_cmf<false, true, false, 4>), gC, blk, 0, stream,
                     B, WTh, WTl, box_b, (const float*)nullptr, CAB, A, 256, 256, PART);
  hipLaunchKernelGGL(k_coef, dim3(320), blk, 0, stream, PART, box_gs, box_gb, CAB);
  hipLaunchKernelGGL((k_cmf<true, true, false, 4>), gC, blk, 0, stream,
                     A, WTh + 589824, WTl + 589824, box_b + 256, (const float*)nullptr, CAB, B, 256, 256, PART);
  hipLaunchKernelGGL(k_coef, dim3(320), blk, 0, stream, PART, box_gs + 256, box_gb + 256, CAB);
  hipLaunchKernelGGL((k_cmf<true, true, false, 4>), gC, blk, 0, stream,
                     B, WTh + 2 * 589824, WTl + 2 * 589824, box_b + 512, (const float*)nullptr, CAB, A, 256, 256, PART);
  hipLaunchKernelGGL(k_coef, dim3(320), blk, 0, stream, PART, box_gs + 512, box_gb + 512, CAB);
  hipLaunchKernelGGL((k_cmf<true, true, false, 4>), gC, blk, 0, stream,
                     A, WTh + 3 * 589824, WTl + 3 * 589824, box_b + 768, (const float*)nullptr, CAB, B, 256, 256, PART);
  hipLaunchKernelGGL(k_coef, dim3(320), blk, 0, stream, PART, box_gs + 768, box_gb + 768, CAB);

  // ---- bbox head: B -> RG (in A)
  hipLaunchKernelGGL((k_cmf<true, false, false, 1>), gC, blk, 0, stream,
                     B, WBh, WBl, bbox_b, (const float*)nullptr, CAB, RG, 8, 4, (double*)nullptr);

  // ---- boxes, gather, NMS
  hipLaunchKernelGGL(k_dbox, dim3(159), blk, 0, stream, RG, scales, BX);
  hipLaunchKernelGGL(k_gather, dim3(40), blk, 0, stream, GAI, CCL, BX, CBX, COB);
  hipLaunchKernelGGL(k_nms, dim3(2), blk, 0, stream, CBX, COB, CSC, CCL, (float*)d_out);
}

// Round 5
// 2165.013 us; speedup vs baseline: 8.8906x; 1.0639x over previous
//
#include <hip/hip_runtime.h>
#include <math.h>

// FCOS RPN head, R5: R4 + register-resident NMS (1024 thr, 2 barriers/iter,
// candidates held in VGPRs, winner published via 10-float LDS slot).
// Conv path (split-f16 MFMA, Ootomo 2-term) unchanged from R4 (passed, 0.0).

#define KCLS 80
#define TOPKK 1000
#define NCAND 5000
#define MAXDET 100
#define TOTHW 20267

constexpr int cHa[5]  = {100, 50, 25, 13, 7};
constexpr int cWa[5]  = {152, 76, 38, 19, 10};
constexpr int cHWa[5] = {15200, 3800, 950, 247, 70};
constexpr int cPa[5]  = {0, 15200, 19000, 19950, 20197};
constexpr int cTXa[5] = {19, 10, 5, 3, 2};
constexpr int cPTa[5] = {0, 247, 317, 337, 343};
constexpr int cTa[5]  = {247, 70, 20, 6, 2};
constexpr float cSa[5] = {8.f, 16.f, 32.f, 64.f, 128.f};
constexpr int cPCh[5] = {0, 238, 298, 313, 317};  // 64-px transpose chunks

typedef _Float16 h8 __attribute__((ext_vector_type(8)));
typedef float f4 __attribute__((ext_vector_type(4)));

struct FeatPtrs { const float* p[5]; };

__device__ __forceinline__ int lvl_of_tile(int bx) {
  return (bx < 247) ? 0 : (bx < 317) ? 1 : (bx < 337) ? 2 : (bx < 343) ? 3 : 4;
}
__device__ __forceinline__ int lvl_of_pix(int gi) {
  return (gi < 15200) ? 0 : (gi < 19000) ? 1 : (gi < 19950) ? 2 : (gi < 20197) ? 3 : 4;
}

// ---------------- feats transpose: [c][H][W] -> FT[n][gi][256] --------------
__global__ __launch_bounds__(256) void k_tf(FeatPtrs fp, float* __restrict__ FT) {
  int b = blockIdx.x, n = blockIdx.y;
  int l = (b < 238) ? 0 : (b < 298) ? 1 : (b < 313) ? 2 : (b < 317) ? 3 : 4;
  int ch = b - cPCh[l];
  int HW = cHWa[l];
  int px0 = ch * 64;
  const float* src = fp.p[l] + (size_t)n * 256 * HW;
  __shared__ float tile[64][65];
  int tid = threadIdx.x;
  int a0 = tid & 63, a1 = tid >> 6;
  for (int icc = 0; icc < 256; icc += 64) {
    __syncthreads();
#pragma unroll
    for (int j = 0; j < 16; ++j) {
      int ic = icc + a1 * 16 + j;
      int px = px0 + a0;
      tile[a0][a1 * 16 + j] = (px < HW) ? src[(size_t)ic * HW + px] : 0.f;
    }
    __syncthreads();
#pragma unroll
    for (int j = 0; j < 16; ++j) {
      int pxl = a1 * 16 + j;
      int px = px0 + pxl;
      if (px < HW)
        FT[((size_t)(n * TOTHW + cPa[l] + px)) * 256 + icc + a0] = tile[pxl][a0];
    }
  }
}

// ---------------- weight repack to MFMA B-fragment order, f16 split ----------
__global__ void k_rep(const float* __restrict__ w, const float* __restrict__ w2,
                      _Float16* __restrict__ Wh, _Float16* __restrict__ Wl,
                      int OC, int OCpad) {
  int i = blockIdx.x * 256 + threadIdx.x;
  int tot = 2304 * OCpad;
  if (i >= tot) return;
  int j = i & 7, kh = (i >> 3) & 3, c = (i >> 5) & 15;
  int rest = i >> 9;
  int G = OCpad >> 4;
  int g = rest % G, ti = rest / G;
  int ics = ti & 7, t = ti >> 3;
  int oc = g * 16 + c, ic = ics * 32 + kh * 8 + j;
  float v = 0.f;
  if (oc < OC) v = w[((size_t)oc * 256 + ic) * 9 + t];
  else if (w2 != nullptr && oc == OC) v = w2[(size_t)ic * 9 + t];
  float sv = v * 2048.f;
  _Float16 h = (_Float16)sv;
  Wh[i] = h;
  Wl[i] = (_Float16)(sv - (float)h);
}

// ---------------- MFMA conv3x3 pad=1 Cin=256, all levels batched -------------
template<bool AFFINE, bool GN_PART, bool HEAD, int NT>
__global__ __launch_bounds__(256) void k_cmf(
    const float* __restrict__ actIn,
    const _Float16* __restrict__ Wh, const _Float16* __restrict__ Wl,
    const float* __restrict__ bias1, const float* __restrict__ bias2,
    const float* __restrict__ cab, float* __restrict__ out,
    int outCH, int OC, double* __restrict__ part) {
  const int bx = blockIdx.x;
  const int lvl = lvl_of_tile(bx);
  const int tile = bx - cPTa[lvl];
  const int H = cHa[lvl], W = cWa[lvl];
  const int tx0 = (tile % cTXa[lvl]) * 8, ty0 = (tile / cTXa[lvl]) * 8;
  const int n = blockIdx.z;
  const int t = threadIdx.x, wv = t >> 6, lane = t & 63;
  const int kh = lane >> 4, c = lane & 15;

  __shared__ _Float16 sH[6400];
  __shared__ _Float16 sL[6400];

  const float* cabL = cab + (size_t)(lvl * 2 + n) * 512;

  const float* sp[4];
  int shp[4], sgp[4];
  bool sinb[4], shas[4];
#pragma unroll
  for (int s = 0; s < 4; ++s) {
    int e = t + 256 * s;
    bool has = e < 800;
    int grp = e & 7, hp = e >> 3;
    if (hp > 99) hp = 99;
    int yy = hp / 10, xx = hp % 10;
    int gy = ty0 + yy - 1, gx = tx0 + xx - 1;
    bool inb = has && ((unsigned)gy < (unsigned)H) && ((unsigned)gx < (unsigned)W);
    int gpx = inb ? (cPa[lvl] + gy * W + gx) : 0;
    sp[s] = actIn + ((size_t)(n * TOTHW + gpx)) * 256 + grp * 8;
    shp[s] = hp; sgp[s] = grp; sinb[s] = inb; shas[s] = has;
  }

  f4 acc[4][NT];
#pragma unroll
  for (int m = 0; m < 4; ++m)
#pragma unroll
    for (int nt = 0; nt < NT; ++nt) acc[m][nt] = (f4)(0.f);

  float4 fv[4][2];
#pragma unroll
  for (int s = 0; s < 4; ++s) {
    if (sinb[s]) {
      fv[s][0] = *(const float4*)(sp[s]);
      fv[s][1] = *(const float4*)(sp[s] + 4);
    } else {
      fv[s][0] = make_float4(0.f, 0.f, 0.f, 0.f);
      fv[s][1] = make_float4(0.f, 0.f, 0.f, 0.f);
    }
  }

  const int lB = (c * 4 + kh) * 8;

#pragma unroll 1
  for (int icc = 0; icc < 256; icc += 64) {
    __syncthreads();
#pragma unroll
    for (int s = 0; s < 4; ++s) {
      if (shas[s]) {
        float vv[8];
        vv[0] = fv[s][0].x; vv[1] = fv[s][0].y; vv[2] = fv[s][0].z; vv[3] = fv[s][0].w;
        vv[4] = fv[s][1].x; vv[5] = fv[s][1].y; vv[6] = fv[s][1].z; vv[7] = fv[s][1].w;
        if (AFFINE && sinb[s]) {
#pragma unroll
          for (int j = 0; j < 8; ++j) {
            int ch = icc + sgp[s] * 8 + j;
            vv[j] = fmaxf(0.f, fmaf(vv[j], cabL[2 * ch], cabL[2 * ch + 1]));
          }
        }
        h8 hv, lv2;
#pragma unroll
        for (int j = 0; j < 8; ++j) {
          float sv = vv[j] * 32.f;
          _Float16 hh = (_Float16)sv;
          hv[j] = hh;
          lv2[j] = (_Float16)(sv - (float)hh);
        }
        int boff = ((shp[s] << 7) + (sgp[s] << 4)) ^ ((shp[s] & 7) << 4);
        *(h8*)((char*)sH + boff) = hv;
        *(h8*)((char*)sL + boff) = lv2;
      }
    }
    if (icc < 192) {
#pragma unroll
      for (int s = 0; s < 4; ++s) {
        if (sinb[s]) {
          fv[s][0] = *(const float4*)(sp[s] + icc + 64);
          fv[s][1] = *(const float4*)(sp[s] + icc + 68);
        }
      }
    }
    __syncthreads();

#pragma unroll 1
    for (int dy = 0; dy < 3; ++dy) {
#pragma unroll 1
      for (int dx = 0; dx < 3; ++dx) {
        const int t9 = dy * 3 + dx;
#pragma unroll
        for (int ics = 0; ics < 2; ++ics) {
          const int ICS = (icc >> 5) + ics;
          size_t wb = ((size_t)(t9 * 8 + ICS) * (NT * 4) + wv * NT) * 512 + lB;
          h8 bh[NT], bl[NT];
#pragma unroll
          for (int nt = 0; nt < NT; ++nt) {
            bh[nt] = *(const h8*)(Wh + wb + nt * 512);
            bl[nt] = *(const h8*)(Wl + wb + nt * 512);
          }
#pragma unroll
          for (int m = 0; m < 4; ++m) {
            int pxA = m * 16 + c;
            int hpA = ((pxA >> 3) + dy) * 10 + (pxA & 7) + dx;
            int boffA = ((hpA << 7) + (ics << 6) + (kh << 4)) ^ ((hpA & 7) << 4);
            h8 Ah = *(const h8*)((const char*)sH + boffA);
            h8 Al = *(const h8*)((const char*)sL + boffA);
#pragma unroll
            for (int nt = 0; nt < NT; ++nt) {
              acc[m][nt] = __builtin_amdgcn_mfma_f32_16x16x32_f16(Ah, bh[nt], acc[m][nt], 0, 0, 0);
              acc[m][nt] = __builtin_amdgcn_mfma_f32_16x16x32_f16(Ah, bl[nt], acc[m][nt], 0, 0, 0);
              acc[m][nt] = __builtin_amdgcn_mfma_f32_16x16x32_f16(Al, bh[nt], acc[m][nt], 0, 0, 0);
            }
          }
        }
      }
    }
  }

  const float inv = 1.f / 65536.f;
#pragma unroll
  for (int nt = 0; nt < NT; ++nt) {
    int oc = wv * (NT * 16) + nt * 16 + c;
    float bb;
    if (HEAD) bb = (oc < KCLS) ? bias1[oc] : (oc == KCLS ? bias2[0] : 0.f);
    else bb = (oc < OC) ? bias1[oc] : 0.f;
    double s = 0.0, ss = 0.0;
#pragma unroll
    for (int m = 0; m < 4; ++m) {
#pragma unroll
      for (int r = 0; r < 4; ++r) {
        int px = m * 16 + kh * 4 + r;
        int oy = ty0 + (px >> 3), ox = tx0 + (px & 7);
        bool vpx = (oy < H) && (ox < W);
        float y = fmaf(acc[m][nt][r], inv, bb);
        if (vpx && oc < OC)
          out[((size_t)(n * TOTHW + cPa[lvl] + oy * W + ox)) * outCH + oc] = y;
        if (GN_PART && vpx) { double d = (double)y; s += d; ss += d * d; }
      }
    }
    if (GN_PART) {
#pragma unroll
      for (int msk = 16; msk <= 32; msk <<= 1) {
        s += __shfl_xor(s, msk, 64);
        ss += __shfl_xor(ss, msk, 64);
      }
#pragma unroll
      for (int msk = 1; msk <= 4; msk <<= 1) {
        s += __shfl_xor(s, msk, 64);
        ss += __shfl_xor(ss, msk, 64);
      }
      if (lane == 0 || lane == 8) {
        int G = wv * 8 + nt * 2 + (lane >> 3);
        size_t sl = (((size_t)bx * 2 + n) * 32 + G) * 2;
        part[sl] = s;
        part[sl + 1] = ss;
      }
    }
  }
}

// ---------------- GN coef from per-tile partials -----------------------------
__global__ __launch_bounds__(256) void k_coef(const double* __restrict__ part,
                                              const float* __restrict__ gs,
                                              const float* __restrict__ gb,
                                              float* __restrict__ cab) {
  int l = blockIdx.x >> 6, ng = blockIdx.x & 63, n = ng >> 5, g = ng & 31;
  int T = cTa[l];
  double s = 0.0, ss = 0.0;
  for (int tt = threadIdx.x; tt < T; tt += 256) {
    size_t sl = (((size_t)(cPTa[l] + tt) * 2 + n) * 32 + g) * 2;
    s += part[sl]; ss += part[sl + 1];
  }
  __shared__ double rs[256], rss[256];
  rs[threadIdx.x] = s; rss[threadIdx.x] = ss;
  __syncthreads();
  for (int off = 128; off > 0; off >>= 1) {
    if (threadIdx.x < off) {
      rs[threadIdx.x] += rs[threadIdx.x + off];
      rss[threadIdx.x] += rss[threadIdx.x + off];
    }
    __syncthreads();
  }
  if (threadIdx.x == 0) {
    int len = 8 * cHWa[l];
    double mu = rs[0] / len;
    double var = rss[0] / len - mu * mu;
    double rsq = 1.0 / sqrt(var + 1e-5);
    for (int cc = 0; cc < 8; ++cc) {
      int ch = g * 8 + cc;
      double A = rsq * (double)gs[ch];
      cab[((size_t)(l * 2 + n) * 256 + ch) * 2] = (float)A;
      cab[((size_t)(l * 2 + n) * 256 + ch) * 2 + 1] = (float)((double)gb[ch] - mu * A);
    }
  }
}

// ---------------- decode scores ---------------------------------------------
__global__ void k_dscore(const float* __restrict__ LG, float* __restrict__ SF) {
  size_t i = (size_t)blockIdx.x * 256 + threadIdx.x;
  size_t tot = (size_t)2 * TOTHW * 80;
  if (i >= tot) return;
  int c = (int)(i % 80);
  size_t g = i / 80;
  const float* base = LG + g * 96;
  float lg = base[c];
  float ct = base[80];
  float s1 = 1.f / (1.f + expf(-lg));
  float s2 = 1.f / (1.f + expf(-ct));
  SF[i] = sqrtf(s1 * s2);
}

// ---------------- decode boxes ----------------------------------------------
__global__ void k_dbox(const float* __restrict__ RG, const float* __restrict__ scales,
                       float* __restrict__ BX) {
  int i = blockIdx.x * 256 + threadIdx.x;
  if (i >= 2 * TOTHW) return;
  int gi = i % TOTHW;
  int l = lvl_of_pix(gi);
  int a = gi - cPa[l];
  int W = cWa[l];
  const float* rg = RG + (size_t)i * 8;
  float sc = scales[l];
  float stride = cSa[l];
  float r0 = fmaxf(0.f, sc * rg[0]);
  float r1 = fmaxf(0.f, sc * rg[1]);
  float r2 = fmaxf(0.f, sc * rg[2]);
  float r3 = fmaxf(0.f, sc * rg[3]);
  int x = a % W, yv = a / W;
  float px = (x + 0.5f) * stride, py = (yv + 0.5f) * stride;
  float* bp = BX + (size_t)i * 4;
  bp[0] = px - r0 * stride; bp[1] = py - r1 * stride;
  bp[2] = px + r2 * stride; bp[3] = py + r3 * stride;
}

// ---------------- exact top-1000 per (n,level) -------------------------------
__global__ void k_hist1(const float* __restrict__ SF, unsigned* __restrict__ hist) {
  int nl = blockIdx.y; int n = nl & 1, l = nl >> 1;
  const float* s = SF + ((size_t)n * TOTHW + cPa[l]) * 80;
  int M = cHWa[l] * 80;
  unsigned* h = hist + nl * 1024;
  __shared__ unsigned lh[1024];
  for (int i = threadIdx.x; i < 1024; i += blockDim.x) lh[i] = 0;
  __syncthreads();
  for (int i = blockIdx.x * blockDim.x + threadIdx.x; i < M; i += gridDim.x * blockDim.x) {
    unsigned key = __float_as_uint(s[i]);
    unsigned b = key >> 20; if (b > 1023u) b = 1023u;
    atomicAdd(&lh[b], 1u);
  }
  __syncthreads();
  for (int i = threadIdx.x; i < 1024; i += blockDim.x)
    if (lh[i]) atomicAdd(&h[i], lh[i]);
}

__global__ void k_resolve1(const unsigned* __restrict__ hist, unsigned* __restrict__ ctl) {
  int nl = threadIdx.x;
  if (nl >= 10) return;
  const unsigned* h = hist + nl * 1024;
  unsigned acc = 0; int b = 1023;
  for (; b > 0; --b) { acc += h[b]; if (acc >= TOPKK) break; }
  if (acc < TOPKK) { acc += h[0]; b = 0; }
  ctl[nl] = (unsigned)b;
  ctl[10 + nl] = acc - h[b];
}

__global__ void k_hist2(const float* __restrict__ SF, const unsigned* __restrict__ ctl,
                        unsigned* __restrict__ hist2) {
  int nl = blockIdx.y; int n = nl & 1, l = nl >> 1;
  unsigned b1 = ctl[nl];
  const float* s = SF + ((size_t)n * TOTHW + cPa[l]) * 80;
  int M = cHWa[l] * 80;
  unsigned* h = hist2 + nl * 4096;
  __shared__ unsigned lh[4096];
  for (int i = threadIdx.x; i < 4096; i += blockDim.x) lh[i] = 0;
  __syncthreads();
  for (int i = blockIdx.x * blockDim.x + threadIdx.x; i < M; i += gridDim.x * blockDim.x) {
    unsigned key = __float_as_uint(s[i]);
    if ((key >> 20) == b1) atomicAdd(&lh[(key >> 8) & 0xFFFu], 1u);
  }
  __syncthreads();
  for (int i = threadIdx.x; i < 4096; i += blockDim.x)
    if (lh[i]) atomicAdd(&h[i], lh[i]);
}

__global__ void k_resolve2(const unsigned* __restrict__ hist2, unsigned* __restrict__ ctl) {
  int nl = threadIdx.x;
  if (nl >= 10) return;
  unsigned b1 = ctl[nl];
  unsigned acc = ctl[10 + nl];
  const unsigned* h = hist2 + nl * 4096;
  int b = 4095;
  for (; b > 0; --b) { acc += h[b]; if (acc >= TOPKK) break; }
  if (acc < TOPKK) b = 0;
  ctl[20 + nl] = (b1 << 12) | (unsigned)b;
}

__device__ __forceinline__ void write_cand(int n, int l, int pos, float v, int i,
                                           float* csc, float* ccl, int* gai) {
  int a = i / KCLS, c = i - a * KCLS;
  int g = n * NCAND + pos;
  csc[g] = (v > 0.05f) ? v : 0.f;
  ccl[g] = (float)c;
  gai[g] = cPa[l] + a;
}

__global__ void k_compact(const float* __restrict__ SF, const unsigned* __restrict__ ctl,
                          unsigned* __restrict__ cnt, float* __restrict__ eqV,
                          unsigned* __restrict__ eqI,
                          float* csc, float* ccl, int* gai) {
  int nl = blockIdx.y; int n = nl & 1, l = nl >> 1;
  const float* s = SF + ((size_t)n * TOTHW + cPa[l]) * 80;
  int M = cHWa[l] * 80;
  unsigned P = ctl[20 + nl];
  int loff = l * TOPKK;
  for (int i = blockIdx.x * blockDim.x + threadIdx.x; i < M; i += gridDim.x * blockDim.x) {
    float v = s[i];
    unsigned k24 = __float_as_uint(v) >> 8;
    if (k24 < P) continue;
    if (k24 > P) {
      unsigned slot = atomicAdd(&cnt[nl], 1u);
      write_cand(n, l, loff + (int)slot, v, i, csc, ccl, gai);
    } else {
      unsigned e = atomicAdd(&cnt[10 + nl], 1u);
      if (e < 2048u) { eqV[nl * 2048 + e] = v; eqI[nl * 2048 + e] = (unsigned)i; }
    }
  }
}

__global__ void k_eq(const float* __restrict__ eqV, const unsigned* __restrict__ eqI,
                     const unsigned* __restrict__ cnt,
                     float* csc, float* ccl, int* gai) {
  int nl = blockIdx.x; int n = nl & 1, l = nl >> 1;
  int above = (int)cnt[nl];
  unsigned ec = cnt[10 + nl];
  int E = ec < 2048u ? (int)ec : 2048;
  int r = TOPKK - above;
  int loff = l * TOPKK;
  for (int e = threadIdx.x; e < E; e += blockDim.x) {
    float v = eqV[nl * 2048 + e];
    unsigned idx = eqI[nl * 2048 + e];
    int rank = 0;
    for (int j = 0; j < E; ++j) {
      float vj = eqV[nl * 2048 + j];
      unsigned ij = eqI[nl * 2048 + j];
      if (vj > v || (vj == v && ij < idx)) rank++;
    }
    if (rank < r)
      write_cand(n, l, loff + above + rank, v, (int)idx, csc, ccl, gai);
  }
}

// ---------------- gather candidate boxes -------------------------------------
__global__ void k_gather(const int* __restrict__ gai, const float* __restrict__ ccl,
                         const float* __restrict__ BX,
                         float* __restrict__ cbx, float* __restrict__ cob) {
  int i = blockIdx.x * 256 + threadIdx.x;
  if (i >= 2 * NCAND) return;
  int n = i / NCAND;
  int a = gai[i];
  if (a < 0 || a >= TOTHW) a = 0;
  const float* bp = BX + ((size_t)n * TOTHW + a) * 4;
  float b0 = bp[0], b1 = bp[1], b2 = bp[2], b3 = bp[3];
  float off = ccl[i] * 1e4f;
  cbx[(size_t)i * 4 + 0] = b0; cbx[(size_t)i * 4 + 1] = b1;
  cbx[(size_t)i * 4 + 2] = b2; cbx[(size_t)i * 4 + 3] = b3;
  cob[(size_t)i * 4 + 0] = b0 + off; cob[(size_t)i * 4 + 1] = b1 + off;
  cob[(size_t)i * 4 + 2] = b2 + off; cob[(size_t)i * 4 + 3] = b3 + off;
}

// ---------------- NMS: register-resident, 1024 thr, 2 barriers/iter ----------
__global__ __launch_bounds__(1024) void k_nms(
    const float* __restrict__ cbox, const float* __restrict__ cscore,
    const float* __restrict__ ccls, float* __restrict__ out) {
  const int n = blockIdx.x;
  const int tid = threadIdx.x;
  const int wid = tid >> 6, lane = tid & 63;
  __shared__ float redV[16];
  __shared__ int redJ[16];
  __shared__ float sOB[10];  // obx(4), area, bx(4), cls

  float sc[5], bxr[5][4], obr[5][4], ar[5], cl[5];
#pragma unroll
  for (int q = 0; q < 5; ++q) {
    int j = q * 1024 + tid;
    if (j < NCAND) {
      size_t g = (size_t)n * NCAND + j;
      sc[q] = cscore[g];
      float4 b = *(const float4*)(cbox + g * 4);
      float cc = ccls[g];
      float off = cc * 1e4f;
      cl[q] = cc;
      bxr[q][0] = b.x; bxr[q][1] = b.y; bxr[q][2] = b.z; bxr[q][3] = b.w;
      obr[q][0] = b.x + off; obr[q][1] = b.y + off;
      obr[q][2] = b.z + off; obr[q][3] = b.w + off;
      ar[q] = fmaxf(obr[q][2] - obr[q][0], 0.f) * fmaxf(obr[q][3] - obr[q][1], 0.f);
    } else {
      sc[q] = -1.f; cl[q] = 0.f;
      bxr[q][0] = bxr[q][1] = bxr[q][2] = bxr[q][3] = 0.f;
      obr[q][0] = 1e30f; obr[q][1] = 1e30f; obr[q][2] = -1e30f; obr[q][3] = -1e30f;
      ar[q] = 0.f;
    }
  }

  for (int it = 0; it < MAXDET; ++it) {
    // local argmax (ascending j, strict > keeps first occurrence)
    float mv = sc[0]; int mj = tid;
#pragma unroll
    for (int q = 1; q < 5; ++q) {
      if (sc[q] > mv) { mv = sc[q]; mj = q * 1024 + tid; }
    }
    // wave butterfly (tie -> smaller global index)
#pragma unroll
    for (int off = 1; off < 64; off <<= 1) {
      float ov = __shfl_xor(mv, off);
      int oj = __shfl_xor(mj, off);
      if (ov > mv || (ov == mv && oj < mj)) { mv = ov; mj = oj; }
    }
    if (lane == 0) { redV[wid] = mv; redJ[wid] = mj; }
    __syncthreads();
    float bv = redV[0]; int bj = redJ[0];
#pragma unroll
    for (int w = 1; w < 16; ++w) {
      float v2 = redV[w]; int j2 = redJ[w];
      if (v2 > bv || (v2 == bv && j2 < bj)) { bv = v2; bj = j2; }
    }
    const bool owner = ((bj & 1023) == tid);
    if (owner) {
      int q = bj >> 10;
      sOB[0] = obr[q][0]; sOB[1] = obr[q][1]; sOB[2] = obr[q][2]; sOB[3] = obr[q][3];
      sOB[4] = ar[q];
      sOB[5] = bxr[q][0]; sOB[6] = bxr[q][1]; sOB[7] = bxr[q][2]; sOB[8] = bxr[q][3];
      sOB[9] = cl[q];
    }
    __syncthreads();
    const bool valid = bv > 0.f;
    if (valid) {
      float ox1 = sOB[0], oy1 = sOB[1], ox2 = sOB[2], oy2 = sOB[3], ai = sOB[4];
#pragma unroll
      for (int q = 0; q < 5; ++q) {
        int j = q * 1024 + tid;
        float iw = fmaxf(fminf(ox2, obr[q][2]) - fmaxf(ox1, obr[q][0]), 0.f);
        float ih = fmaxf(fminf(oy2, obr[q][3]) - fmaxf(oy1, obr[q][1]), 0.f);
        float inter = iw * ih;
        float iou = inter / fmaxf(ai + ar[q] - inter, 1e-6f);
        if (iou > 0.6f || j == bj) sc[q] = 0.f;
      }
      if (owner) {
        float* o = out + ((size_t)n * MAXDET + it) * 6;
        o[0] = sOB[5]; o[1] = sOB[6]; o[2] = sOB[7]; o[3] = sOB[8];
        o[4] = bv; o[5] = sOB[9];
      }
    } else if (tid == 0) {
      float* o = out + ((size_t)n * MAXDET + it) * 6;
      o[0] = o[1] = o[2] = o[3] = o[4] = o[5] = 0.f;
    }
  }
}

// ---------------- host orchestration -----------------------------------------
extern "C" void kernel_launch(void* const* d_in, const int* in_sizes, int n_in,
                              void* d_out, int out_size, void* d_ws, size_t ws_size,
                              hipStream_t stream) {
  FeatPtrs fp;
  for (int i = 0; i < 5; ++i) fp.p[i] = (const float*)d_in[i];
  const float* cls_w = (const float*)d_in[5];
  const float* cls_b = (const float*)d_in[6];
  const float* cls_gs = (const float*)d_in[7];
  const float* cls_gb = (const float*)d_in[8];
  const float* box_w = (const float*)d_in[9];
  const float* box_b = (const float*)d_in[10];
  const float* box_gs = (const float*)d_in[11];
  const float* box_gb = (const float*)d_in[12];
  const float* score_w = (const float*)d_in[13];
  const float* score_b = (const float*)d_in[14];
  const float* bbox_w = (const float*)d_in[15];
  const float* bbox_b = (const float*)d_in[16];
  const float* ctr_w = (const float*)d_in[17];
  const float* ctr_b = (const float*)d_in[18];
  const float* scales = (const float*)d_in[19];

  float* ws = (float*)d_ws;
  const size_t A_off    = 0;           // 10,376,704
  const size_t B_off    = 10376704;    // 10,376,704 (also feats-transpose FT)
  const size_t WTh_off  = 20753408;    // 1,179,648
  const size_t WTl_off  = 21933056;    // 1,179,648
  const size_t WSh_off  = 23112704;    // 147,456
  const size_t WSl_off  = 23260160;    // 147,456
  const size_t WBh_off  = 23407616;    // 73,728
  const size_t WBl_off  = 23481344;    // 73,728
  const size_t PART_off = 23555072;    // 176,640 (88,320 doubles)
  const size_t CAB_off  = 23731712;    // 5,120
  const size_t CSC_off  = 23736832;    // 10,000
  const size_t CCL_off  = 23746832;    // 10,000
  const size_t GAI_off  = 23756832;    // 10,000
  const size_t H1_off   = 23766832;    // 10,240
  const size_t H2_off   = 23777072;    // 40,960
  const size_t CNT_off  = 23818032;    // 32
  const size_t CTL_off  = 23818064;    // 32
  const size_t EQV_off  = 23818096;    // 20,480
  const size_t EQI_off  = 23838576;    // 20,480
  const size_t LG_off   = A_off + 0;
  const size_t SF_off   = A_off + 4000000;
  const size_t RG_off   = A_off + 7300000;
  const size_t BX_off   = A_off + 7700000;
  const size_t CBX_off  = A_off + 7900000;
  const size_t COB_off  = A_off + 7950000;

  float* A = ws + A_off;
  float* B = ws + B_off;
  _Float16* WTh = (_Float16*)(ws + WTh_off);
  _Float16* WTl = (_Float16*)(ws + WTl_off);
  _Float16* WSh = (_Float16*)(ws + WSh_off);
  _Float16* WSl = (_Float16*)(ws + WSl_off);
  _Float16* WBh = (_Float16*)(ws + WBh_off);
  _Float16* WBl = (_Float16*)(ws + WBl_off);
  double* PART = (double*)(ws + PART_off);
  float* CAB = ws + CAB_off;
  float* CSC = ws + CSC_off;
  float* CCL = ws + CCL_off;
  int* GAI = (int*)(ws + GAI_off);
  unsigned* H1 = (unsigned*)(ws + H1_off);
  unsigned* H2 = (unsigned*)(ws + H2_off);
  unsigned* CNT = (unsigned*)(ws + CNT_off);
  unsigned* CTL = (unsigned*)(ws + CTL_off);
  float* EQV = ws + EQV_off;
  unsigned* EQI = (unsigned*)(ws + EQI_off);
  float* LG = ws + LG_off;
  float* SF = ws + SF_off;
  float* RG = ws + RG_off;
  float* BX = ws + BX_off;
  float* CBX = ws + CBX_off;
  float* COB = ws + COB_off;

  hipMemsetAsync(CSC, 0, (CTL_off + 32 - CSC_off) * sizeof(float), stream);

  dim3 blk(256);
  for (int ll = 0; ll < 4; ++ll)
    hipLaunchKernelGGL(k_rep, dim3(2304), blk, 0, stream,
                       cls_w + (size_t)ll * 589824, (const float*)nullptr,
                       WTh + (size_t)ll * 589824, WTl + (size_t)ll * 589824, 256, 256);
  hipLaunchKernelGGL(k_rep, dim3(1152), blk, 0, stream, score_w, ctr_w, WSh, WSl, 80, 128);
  hipLaunchKernelGGL(k_rep, dim3(576), blk, 0, stream, bbox_w, (const float*)nullptr,
                     WBh, WBl, 4, 64);

  hipLaunchKernelGGL(k_tf, dim3(319, 2), blk, 0, stream, fp, B);

  dim3 gC(345, 1, 2);
  // ---- cls tower
  hipLaunchKernelGGL((k_cmf<false, true, false, 4>), gC, blk, 0, stream,
                     B, WTh, WTl, cls_b, (const float*)nullptr, CAB, A, 256, 256, PART);
  hipLaunchKernelGGL(k_coef, dim3(320), blk, 0, stream, PART, cls_gs, cls_gb, CAB);
  hipLaunchKernelGGL((k_cmf<true, true, false, 4>), gC, blk, 0, stream,
                     A, WTh + 589824, WTl + 589824, cls_b + 256, (const float*)nullptr, CAB, B, 256, 256, PART);
  hipLaunchKernelGGL(k_coef, dim3(320), blk, 0, stream, PART, cls_gs + 256, cls_gb + 256, CAB);
  hipLaunchKernelGGL((k_cmf<true, true, false, 4>), gC, blk, 0, stream,
                     B, WTh + 2 * 589824, WTl + 2 * 589824, cls_b + 512, (const float*)nullptr, CAB, A, 256, 256, PART);
  hipLaunchKernelGGL(k_coef, dim3(320), blk, 0, stream, PART, cls_gs + 512, cls_gb + 512, CAB);
  hipLaunchKernelGGL((k_cmf<true, true, false, 4>), gC, blk, 0, stream,
                     A, WTh + 3 * 589824, WTl + 3 * 589824, cls_b + 768, (const float*)nullptr, CAB, B, 256, 256, PART);
  hipLaunchKernelGGL(k_coef, dim3(320), blk, 0, stream, PART, cls_gs + 768, cls_gb + 768, CAB);

  // ---- score+ctr head: B -> LG (in A)
  hipLaunchKernelGGL((k_cmf<true, false, true, 2>), gC, blk, 0, stream,
                     B, WSh, WSl, score_b, ctr_b, CAB, LG, 96, 81, (double*)nullptr);

  // ---- scores + exact top-1000
  hipLaunchKernelGGL(k_dscore, dim3(12667), blk, 0, stream, LG, SF);
  hipLaunchKernelGGL(k_hist1, dim3(128, 10), blk, 0, stream, SF, H1);
  hipLaunchKernelGGL(k_resolve1, dim3(1), dim3(64), 0, stream, H1, CTL);
  hipLaunchKernelGGL(k_hist2, dim3(128, 10), blk, 0, stream, SF, CTL, H2);
  hipLaunchKernelGGL(k_resolve2, dim3(1), dim3(64), 0, stream, H2, CTL);
  hipLaunchKernelGGL(k_compact, dim3(128, 10), blk, 0, stream, SF, CTL, CNT, EQV, EQI, CSC, CCL, GAI);
  hipLaunchKernelGGL(k_eq, dim3(10), blk, 0, stream, EQV, EQI, CNT, CSC, CCL, GAI);

  // ---- box tower weights + re-transpose feats
  for (int ll = 0; ll < 4; ++ll)
    hipLaunchKernelGGL(k_rep, dim3(2304), blk, 0, stream,
                       box_w + (size_t)ll * 589824, (const float*)nullptr,
                       WTh + (size_t)ll * 589824, WTl + (size_t)ll * 589824, 256, 256);
  hipLaunchKernelGGL(k_tf, dim3(319, 2), blk, 0, stream, fp, B);

  // ---- box tower
  hipLaunchKernelGGL((k_cmf<false, true, false, 4>), gC, blk, 0, stream,
                     B, WTh, WTl, box_b, (const float*)nullptr, CAB, A, 256, 256, PART);
  hipLaunchKernelGGL(k_coef, dim3(320), blk, 0, stream, PART, box_gs, box_gb, CAB);
  hipLaunchKernelGGL((k_cmf<true, true, false, 4>), gC, blk, 0, stream,
                     A, WTh + 589824, WTl + 589824, box_b + 256, (const float*)nullptr, CAB, B, 256, 256, PART);
  hipLaunchKernelGGL(k_coef, dim3(320), blk, 0, stream, PART, box_gs + 256, box_gb + 256, CAB);
  hipLaunchKernelGGL((k_cmf<true, true, false, 4>), gC, blk, 0, stream,
                     B, WTh + 2 * 589824, WTl + 2 * 589824, box_b + 512, (const float*)nullptr, CAB, A, 256, 256, PART);
  hipLaunchKernelGGL(k_coef, dim3(320), blk, 0, stream, PART, box_gs + 512, box_gb + 512, CAB);
  hipLaunchKernelGGL((k_cmf<true, true, false, 4>), gC, blk, 0, stream,
                     A, WTh + 3 * 589824, WTl + 3 * 589824, box_b + 768, (const float*)nullptr, CAB, B, 256, 256, PART);
  hipLaunchKernelGGL(k_coef, dim3(320), blk, 0, stream, PART, box_gs + 768, box_gb + 768, CAB);

  // ---- bbox head: B -> RG (in A)
  hipLaunchKernelGGL((k_cmf<true, false, false, 1>), gC, blk, 0, stream,
                     B, WBh, WBl, bbox_b, (const float*)nullptr, CAB, RG, 8, 4, (double*)nullptr);

  // ---- boxes, gather, NMS
  hipLaunchKernelGGL(k_dbox, dim3(159), blk, 0, stream, RG, scales, BX);
  hipLaunchKernelGGL(k_gather, dim3(40), blk, 0, stream, GAI, CCL, BX, CBX, COB);
  hipLaunchKernelGGL(k_nms, dim3(2), dim3(1024), 0, stream, CBX, CSC, CCL, (float*)d_out);
}

// Round 6
// 1838.629 us; speedup vs baseline: 10.4689x; 1.1775x over previous
//
#include <hip/hip_runtime.h>
#include <math.h>

// FCOS RPN head, R6: R5 + parallel suffix-scan resolve kernels (the serial
// descending-histogram loops were 425us of pure load latency on 10 threads).
// Conv path (split-f16 MFMA) and register NMS unchanged (passed, 0.0).

#define KCLS 80
#define TOPKK 1000
#define NCAND 5000
#define MAXDET 100
#define TOTHW 20267

constexpr int cHa[5]  = {100, 50, 25, 13, 7};
constexpr int cWa[5]  = {152, 76, 38, 19, 10};
constexpr int cHWa[5] = {15200, 3800, 950, 247, 70};
constexpr int cPa[5]  = {0, 15200, 19000, 19950, 20197};
constexpr int cTXa[5] = {19, 10, 5, 3, 2};
constexpr int cPTa[5] = {0, 247, 317, 337, 343};
constexpr int cTa[5]  = {247, 70, 20, 6, 2};
constexpr float cSa[5] = {8.f, 16.f, 32.f, 64.f, 128.f};
constexpr int cPCh[5] = {0, 238, 298, 313, 317};  // 64-px transpose chunks

typedef _Float16 h8 __attribute__((ext_vector_type(8)));
typedef float f4 __attribute__((ext_vector_type(4)));

struct FeatPtrs { const float* p[5]; };

__device__ __forceinline__ int lvl_of_tile(int bx) {
  return (bx < 247) ? 0 : (bx < 317) ? 1 : (bx < 337) ? 2 : (bx < 343) ? 3 : 4;
}
__device__ __forceinline__ int lvl_of_pix(int gi) {
  return (gi < 15200) ? 0 : (gi < 19000) ? 1 : (gi < 19950) ? 2 : (gi < 20197) ? 3 : 4;
}

// ---------------- feats transpose: [c][H][W] -> FT[n][gi][256] --------------
__global__ __launch_bounds__(256) void k_tf(FeatPtrs fp, float* __restrict__ FT) {
  int b = blockIdx.x, n = blockIdx.y;
  int l = (b < 238) ? 0 : (b < 298) ? 1 : (b < 313) ? 2 : (b < 317) ? 3 : 4;
  int ch = b - cPCh[l];
  int HW = cHWa[l];
  int px0 = ch * 64;
  const float* src = fp.p[l] + (size_t)n * 256 * HW;
  __shared__ float tile[64][65];
  int tid = threadIdx.x;
  int a0 = tid & 63, a1 = tid >> 6;
  for (int icc = 0; icc < 256; icc += 64) {
    __syncthreads();
#pragma unroll
    for (int j = 0; j < 16; ++j) {
      int ic = icc + a1 * 16 + j;
      int px = px0 + a0;
      tile[a0][a1 * 16 + j] = (px < HW) ? src[(size_t)ic * HW + px] : 0.f;
    }
    __syncthreads();
#pragma unroll
    for (int j = 0; j < 16; ++j) {
      int pxl = a1 * 16 + j;
      int px = px0 + pxl;
      if (px < HW)
        FT[((size_t)(n * TOTHW + cPa[l] + px)) * 256 + icc + a0] = tile[pxl][a0];
    }
  }
}

// ---------------- weight repack to MFMA B-fragment order, f16 split ----------
__global__ void k_rep(const float* __restrict__ w, const float* __restrict__ w2,
                      _Float16* __restrict__ Wh, _Float16* __restrict__ Wl,
                      int OC, int OCpad) {
  int i = blockIdx.x * 256 + threadIdx.x;
  int tot = 2304 * OCpad;
  if (i >= tot) return;
  int j = i & 7, kh = (i >> 3) & 3, c = (i >> 5) & 15;
  int rest = i >> 9;
  int G = OCpad >> 4;
  int g = rest % G, ti = rest / G;
  int ics = ti & 7, t = ti >> 3;
  int oc = g * 16 + c, ic = ics * 32 + kh * 8 + j;
  float v = 0.f;
  if (oc < OC) v = w[((size_t)oc * 256 + ic) * 9 + t];
  else if (w2 != nullptr && oc == OC) v = w2[(size_t)ic * 9 + t];
  float sv = v * 2048.f;
  _Float16 h = (_Float16)sv;
  Wh[i] = h;
  Wl[i] = (_Float16)(sv - (float)h);
}

// ---------------- MFMA conv3x3 pad=1 Cin=256, all levels batched -------------
template<bool AFFINE, bool GN_PART, bool HEAD, int NT>
__global__ __launch_bounds__(256) void k_cmf(
    const float* __restrict__ actIn,
    const _Float16* __restrict__ Wh, const _Float16* __restrict__ Wl,
    const float* __restrict__ bias1, const float* __restrict__ bias2,
    const float* __restrict__ cab, float* __restrict__ out,
    int outCH, int OC, double* __restrict__ part) {
  const int bx = blockIdx.x;
  const int lvl = lvl_of_tile(bx);
  const int tile = bx - cPTa[lvl];
  const int H = cHa[lvl], W = cWa[lvl];
  const int tx0 = (tile % cTXa[lvl]) * 8, ty0 = (tile / cTXa[lvl]) * 8;
  const int n = blockIdx.z;
  const int t = threadIdx.x, wv = t >> 6, lane = t & 63;
  const int kh = lane >> 4, c = lane & 15;

  __shared__ _Float16 sH[6400];
  __shared__ _Float16 sL[6400];

  const float* cabL = cab + (size_t)(lvl * 2 + n) * 512;

  const float* sp[4];
  int shp[4], sgp[4];
  bool sinb[4], shas[4];
#pragma unroll
  for (int s = 0; s < 4; ++s) {
    int e = t + 256 * s;
    bool has = e < 800;
    int grp = e & 7, hp = e >> 3;
    if (hp > 99) hp = 99;
    int yy = hp / 10, xx = hp % 10;
    int gy = ty0 + yy - 1, gx = tx0 + xx - 1;
    bool inb = has && ((unsigned)gy < (unsigned)H) && ((unsigned)gx < (unsigned)W);
    int gpx = inb ? (cPa[lvl] + gy * W + gx) : 0;
    sp[s] = actIn + ((size_t)(n * TOTHW + gpx)) * 256 + grp * 8;
    shp[s] = hp; sgp[s] = grp; sinb[s] = inb; shas[s] = has;
  }

  f4 acc[4][NT];
#pragma unroll
  for (int m = 0; m < 4; ++m)
#pragma unroll
    for (int nt = 0; nt < NT; ++nt) acc[m][nt] = (f4)(0.f);

  float4 fv[4][2];
#pragma unroll
  for (int s = 0; s < 4; ++s) {
    if (sinb[s]) {
      fv[s][0] = *(const float4*)(sp[s]);
      fv[s][1] = *(const float4*)(sp[s] + 4);
    } else {
      fv[s][0] = make_float4(0.f, 0.f, 0.f, 0.f);
      fv[s][1] = make_float4(0.f, 0.f, 0.f, 0.f);
    }
  }

  const int lB = (c * 4 + kh) * 8;

#pragma unroll 1
  for (int icc = 0; icc < 256; icc += 64) {
    __syncthreads();
#pragma unroll
    for (int s = 0; s < 4; ++s) {
      if (shas[s]) {
        float vv[8];
        vv[0] = fv[s][0].x; vv[1] = fv[s][0].y; vv[2] = fv[s][0].z; vv[3] = fv[s][0].w;
        vv[4] = fv[s][1].x; vv[5] = fv[s][1].y; vv[6] = fv[s][1].z; vv[7] = fv[s][1].w;
        if (AFFINE && sinb[s]) {
#pragma unroll
          for (int j = 0; j < 8; ++j) {
            int ch = icc + sgp[s] * 8 + j;
            vv[j] = fmaxf(0.f, fmaf(vv[j], cabL[2 * ch], cabL[2 * ch + 1]));
          }
        }
        h8 hv, lv2;
#pragma unroll
        for (int j = 0; j < 8; ++j) {
          float sv = vv[j] * 32.f;
          _Float16 hh = (_Float16)sv;
          hv[j] = hh;
          lv2[j] = (_Float16)(sv - (float)hh);
        }
        int boff = ((shp[s] << 7) + (sgp[s] << 4)) ^ ((shp[s] & 7) << 4);
        *(h8*)((char*)sH + boff) = hv;
        *(h8*)((char*)sL + boff) = lv2;
      }
    }
    if (icc < 192) {
#pragma unroll
      for (int s = 0; s < 4; ++s) {
        if (sinb[s]) {
          fv[s][0] = *(const float4*)(sp[s] + icc + 64);
          fv[s][1] = *(const float4*)(sp[s] + icc + 68);
        }
      }
    }
    __syncthreads();

#pragma unroll 1
    for (int dy = 0; dy < 3; ++dy) {
#pragma unroll 1
      for (int dx = 0; dx < 3; ++dx) {
        const int t9 = dy * 3 + dx;
#pragma unroll
        for (int ics = 0; ics < 2; ++ics) {
          const int ICS = (icc >> 5) + ics;
          size_t wb = ((size_t)(t9 * 8 + ICS) * (NT * 4) + wv * NT) * 512 + lB;
          h8 bh[NT], bl[NT];
#pragma unroll
          for (int nt = 0; nt < NT; ++nt) {
            bh[nt] = *(const h8*)(Wh + wb + nt * 512);
            bl[nt] = *(const h8*)(Wl + wb + nt * 512);
          }
#pragma unroll
          for (int m = 0; m < 4; ++m) {
            int pxA = m * 16 + c;
            int hpA = ((pxA >> 3) + dy) * 10 + (pxA & 7) + dx;
            int boffA = ((hpA << 7) + (ics << 6) + (kh << 4)) ^ ((hpA & 7) << 4);
            h8 Ah = *(const h8*)((const char*)sH + boffA);
            h8 Al = *(const h8*)((const char*)sL + boffA);
#pragma unroll
            for (int nt = 0; nt < NT; ++nt) {
              acc[m][nt] = __builtin_amdgcn_mfma_f32_16x16x32_f16(Ah, bh[nt], acc[m][nt], 0, 0, 0);
              acc[m][nt] = __builtin_amdgcn_mfma_f32_16x16x32_f16(Ah, bl[nt], acc[m][nt], 0, 0, 0);
              acc[m][nt] = __builtin_amdgcn_mfma_f32_16x16x32_f16(Al, bh[nt], acc[m][nt], 0, 0, 0);
            }
          }
        }
      }
    }
  }

  const float inv = 1.f / 65536.f;
#pragma unroll
  for (int nt = 0; nt < NT; ++nt) {
    int oc = wv * (NT * 16) + nt * 16 + c;
    float bb;
    if (HEAD) bb = (oc < KCLS) ? bias1[oc] : (oc == KCLS ? bias2[0] : 0.f);
    else bb = (oc < OC) ? bias1[oc] : 0.f;
    double s = 0.0, ss = 0.0;
#pragma unroll
    for (int m = 0; m < 4; ++m) {
#pragma unroll
      for (int r = 0; r < 4; ++r) {
        int px = m * 16 + kh * 4 + r;
        int oy = ty0 + (px >> 3), ox = tx0 + (px & 7);
        bool vpx = (oy < H) && (ox < W);
        float y = fmaf(acc[m][nt][r], inv, bb);
        if (vpx && oc < OC)
          out[((size_t)(n * TOTHW + cPa[lvl] + oy * W + ox)) * outCH + oc] = y;
        if (GN_PART && vpx) { double d = (double)y; s += d; ss += d * d; }
      }
    }
    if (GN_PART) {
#pragma unroll
      for (int msk = 16; msk <= 32; msk <<= 1) {
        s += __shfl_xor(s, msk, 64);
        ss += __shfl_xor(ss, msk, 64);
      }
#pragma unroll
      for (int msk = 1; msk <= 4; msk <<= 1) {
        s += __shfl_xor(s, msk, 64);
        ss += __shfl_xor(ss, msk, 64);
      }
      if (lane == 0 || lane == 8) {
        int G = wv * 8 + nt * 2 + (lane >> 3);
        size_t sl = (((size_t)bx * 2 + n) * 32 + G) * 2;
        part[sl] = s;
        part[sl + 1] = ss;
      }
    }
  }
}

// ---------------- GN coef from per-tile partials -----------------------------
__global__ __launch_bounds__(256) void k_coef(const double* __restrict__ part,
                                              const float* __restrict__ gs,
                                              const float* __restrict__ gb,
                                              float* __restrict__ cab) {
  int l = blockIdx.x >> 6, ng = blockIdx.x & 63, n = ng >> 5, g = ng & 31;
  int T = cTa[l];
  double s = 0.0, ss = 0.0;
  for (int tt = threadIdx.x; tt < T; tt += 256) {
    size_t sl = (((size_t)(cPTa[l] + tt) * 2 + n) * 32 + g) * 2;
    s += part[sl]; ss += part[sl + 1];
  }
  __shared__ double rs[256], rss[256];
  rs[threadIdx.x] = s; rss[threadIdx.x] = ss;
  __syncthreads();
  for (int off = 128; off > 0; off >>= 1) {
    if (threadIdx.x < off) {
      rs[threadIdx.x] += rs[threadIdx.x + off];
      rss[threadIdx.x] += rss[threadIdx.x + off];
    }
    __syncthreads();
  }
  if (threadIdx.x == 0) {
    int len = 8 * cHWa[l];
    double mu = rs[0] / len;
    double var = rss[0] / len - mu * mu;
    double rsq = 1.0 / sqrt(var + 1e-5);
    for (int cc = 0; cc < 8; ++cc) {
      int ch = g * 8 + cc;
      double A = rsq * (double)gs[ch];
      cab[((size_t)(l * 2 + n) * 256 + ch) * 2] = (float)A;
      cab[((size_t)(l * 2 + n) * 256 + ch) * 2 + 1] = (float)((double)gb[ch] - mu * A);
    }
  }
}

// ---------------- decode scores ---------------------------------------------
__global__ void k_dscore(const float* __restrict__ LG, float* __restrict__ SF) {
  size_t i = (size_t)blockIdx.x * 256 + threadIdx.x;
  size_t tot = (size_t)2 * TOTHW * 80;
  if (i >= tot) return;
  int c = (int)(i % 80);
  size_t g = i / 80;
  const float* base = LG + g * 96;
  float lg = base[c];
  float ct = base[80];
  float s1 = 1.f / (1.f + expf(-lg));
  float s2 = 1.f / (1.f + expf(-ct));
  SF[i] = sqrtf(s1 * s2);
}

// ---------------- decode boxes ----------------------------------------------
__global__ void k_dbox(const float* __restrict__ RG, const float* __restrict__ scales,
                       float* __restrict__ BX) {
  int i = blockIdx.x * 256 + threadIdx.x;
  if (i >= 2 * TOTHW) return;
  int gi = i % TOTHW;
  int l = lvl_of_pix(gi);
  int a = gi - cPa[l];
  int W = cWa[l];
  const float* rg = RG + (size_t)i * 8;
  float sc = scales[l];
  float stride = cSa[l];
  float r0 = fmaxf(0.f, sc * rg[0]);
  float r1 = fmaxf(0.f, sc * rg[1]);
  float r2 = fmaxf(0.f, sc * rg[2]);
  float r3 = fmaxf(0.f, sc * rg[3]);
  int x = a % W, yv = a / W;
  float px = (x + 0.5f) * stride, py = (yv + 0.5f) * stride;
  float* bp = BX + (size_t)i * 4;
  bp[0] = px - r0 * stride; bp[1] = py - r1 * stride;
  bp[2] = px + r2 * stride; bp[3] = py + r3 * stride;
}

// ---------------- exact top-1000 per (n,level) -------------------------------
__global__ void k_hist1(const float* __restrict__ SF, unsigned* __restrict__ hist) {
  int nl = blockIdx.y; int n = nl & 1, l = nl >> 1;
  const float* s = SF + ((size_t)n * TOTHW + cPa[l]) * 80;
  int M = cHWa[l] * 80;
  unsigned* h = hist + nl * 1024;
  __shared__ unsigned lh[1024];
  for (int i = threadIdx.x; i < 1024; i += blockDim.x) lh[i] = 0;
  __syncthreads();
  for (int i = blockIdx.x * blockDim.x + threadIdx.x; i < M; i += gridDim.x * blockDim.x) {
    unsigned key = __float_as_uint(s[i]);
    unsigned b = key >> 20; if (b > 1023u) b = 1023u;
    atomicAdd(&lh[b], 1u);
  }
  __syncthreads();
  for (int i = threadIdx.x; i < 1024; i += blockDim.x)
    if (lh[i]) atomicAdd(&h[i], lh[i]);
}

// parallel suffix-scan resolve1: b* = max{b : S(b) >= K}; m1 = S(b*+1)
__global__ __launch_bounds__(256) void k_resolve1(const unsigned* __restrict__ hist,
                                                  unsigned* __restrict__ ctl) {
  int nl = blockIdx.x;
  const unsigned* h = hist + nl * 1024;
  int t = threadIdx.x;
  unsigned loc[4];
  unsigned chunk = 0;
#pragma unroll
  for (int j = 0; j < 4; ++j) { loc[j] = h[t * 4 + j]; chunk += loc[j]; }
  __shared__ unsigned csum[256];
  csum[t] = chunk;
  __syncthreads();
  for (int off = 1; off < 256; off <<= 1) {
    unsigned v = (t + off < 256) ? csum[t + off] : 0u;
    __syncthreads();
    csum[t] += v;
    __syncthreads();
  }
  unsigned above = csum[t] - chunk;  // S(4t+4)
  unsigned sfx[5];
  sfx[4] = above;
#pragma unroll
  for (int j = 3; j >= 0; --j) sfx[j] = sfx[j + 1] + loc[j];
#pragma unroll
  for (int j = 0; j < 4; ++j) {
    if (sfx[j] >= TOPKK && sfx[j + 1] < TOPKK) {
      ctl[nl] = (unsigned)(t * 4 + j);
      ctl[10 + nl] = sfx[j + 1];
    }
  }
}

__global__ void k_hist2(const float* __restrict__ SF, const unsigned* __restrict__ ctl,
                        unsigned* __restrict__ hist2) {
  int nl = blockIdx.y; int n = nl & 1, l = nl >> 1;
  unsigned b1 = ctl[nl];
  const float* s = SF + ((size_t)n * TOTHW + cPa[l]) * 80;
  int M = cHWa[l] * 80;
  unsigned* h = hist2 + nl * 4096;
  __shared__ unsigned lh[4096];
  for (int i = threadIdx.x; i < 4096; i += blockDim.x) lh[i] = 0;
  __syncthreads();
  for (int i = blockIdx.x * blockDim.x + threadIdx.x; i < M; i += gridDim.x * blockDim.x) {
    unsigned key = __float_as_uint(s[i]);
    if ((key >> 20) == b1) atomicAdd(&lh[(key >> 8) & 0xFFFu], 1u);
  }
  __syncthreads();
  for (int i = threadIdx.x; i < 4096; i += blockDim.x)
    if (lh[i]) atomicAdd(&h[i], lh[i]);
}

// parallel suffix-scan resolve2: b2* = max{b : m1 + S2(b) >= K}
__global__ __launch_bounds__(256) void k_resolve2(const unsigned* __restrict__ hist2,
                                                  const unsigned* __restrict__ ctlin,
                                                  unsigned* __restrict__ ctl) {
  int nl = blockIdx.x;
  const unsigned* h = hist2 + nl * 4096;
  unsigned b1 = ctlin[nl];
  unsigned m1 = ctlin[10 + nl];
  int t = threadIdx.x;
  unsigned loc[16];
  unsigned chunk = 0;
#pragma unroll
  for (int j = 0; j < 16; ++j) { loc[j] = h[t * 16 + j]; chunk += loc[j]; }
  __shared__ unsigned csum[256];
  csum[t] = chunk;
  __syncthreads();
  for (int off = 1; off < 256; off <<= 1) {
    unsigned v = (t + off < 256) ? csum[t + off] : 0u;
    __syncthreads();
    csum[t] += v;
    __syncthreads();
  }
  unsigned above = csum[t] - chunk;
  unsigned sfx[17];
  sfx[16] = above;
#pragma unroll
  for (int j = 15; j >= 0; --j) sfx[j] = sfx[j + 1] + loc[j];
#pragma unroll
  for (int j = 0; j < 16; ++j) {
    if (m1 + sfx[j] >= TOPKK && m1 + sfx[j + 1] < TOPKK)
      ctl[20 + nl] = (b1 << 12) | (unsigned)(t * 16 + j);
  }
}

__device__ __forceinline__ void write_cand(int n, int l, int pos, float v, int i,
                                           float* csc, float* ccl, int* gai) {
  int a = i / KCLS, c = i - a * KCLS;
  int g = n * NCAND + pos;
  csc[g] = (v > 0.05f) ? v : 0.f;
  ccl[g] = (float)c;
  gai[g] = cPa[l] + a;
}

__global__ void k_compact(const float* __restrict__ SF, const unsigned* __restrict__ ctl,
                          unsigned* __restrict__ cnt, float* __restrict__ eqV,
                          unsigned* __restrict__ eqI,
                          float* csc, float* ccl, int* gai) {
  int nl = blockIdx.y; int n = nl & 1, l = nl >> 1;
  const float* s = SF + ((size_t)n * TOTHW + cPa[l]) * 80;
  int M = cHWa[l] * 80;
  unsigned P = ctl[20 + nl];
  int loff = l * TOPKK;
  for (int i = blockIdx.x * blockDim.x + threadIdx.x; i < M; i += gridDim.x * blockDim.x) {
    float v = s[i];
    unsigned k24 = __float_as_uint(v) >> 8;
    if (k24 < P) continue;
    if (k24 > P) {
      unsigned slot = atomicAdd(&cnt[nl], 1u);
      write_cand(n, l, loff + (int)slot, v, i, csc, ccl, gai);
    } else {
      unsigned e = atomicAdd(&cnt[10 + nl], 1u);
      if (e < 2048u) { eqV[nl * 2048 + e] = v; eqI[nl * 2048 + e] = (unsigned)i; }
    }
  }
}

__global__ void k_eq(const float* __restrict__ eqV, const unsigned* __restrict__ eqI,
                     const unsigned* __restrict__ cnt,
                     float* csc, float* ccl, int* gai) {
  int nl = blockIdx.x; int n = nl & 1, l = nl >> 1;
  int above = (int)cnt[nl];
  unsigned ec = cnt[10 + nl];
  int E = ec < 2048u ? (int)ec : 2048;
  int r = TOPKK - above;
  int loff = l * TOPKK;
  for (int e = threadIdx.x; e < E; e += blockDim.x) {
    float v = eqV[nl * 2048 + e];
    unsigned idx = eqI[nl * 2048 + e];
    int rank = 0;
    for (int j = 0; j < E; ++j) {
      float vj = eqV[nl * 2048 + j];
      unsigned ij = eqI[nl * 2048 + j];
      if (vj > v || (vj == v && ij < idx)) rank++;
    }
    if (rank < r)
      write_cand(n, l, loff + above + rank, v, (int)idx, csc, ccl, gai);
  }
}

// ---------------- gather candidate boxes -------------------------------------
__global__ void k_gather(const int* __restrict__ gai, const float* __restrict__ ccl,
                         const float* __restrict__ BX,
                         float* __restrict__ cbx, float* __restrict__ cob) {
  int i = blockIdx.x * 256 + threadIdx.x;
  if (i >= 2 * NCAND) return;
  int n = i / NCAND;
  int a = gai[i];
  if (a < 0 || a >= TOTHW) a = 0;
  const float* bp = BX + ((size_t)n * TOTHW + a) * 4;
  float b0 = bp[0], b1 = bp[1], b2 = bp[2], b3 = bp[3];
  float off = ccl[i] * 1e4f;
  cbx[(size_t)i * 4 + 0] = b0; cbx[(size_t)i * 4 + 1] = b1;
  cbx[(size_t)i * 4 + 2] = b2; cbx[(size_t)i * 4 + 3] = b3;
  cob[(size_t)i * 4 + 0] = b0 + off; cob[(size_t)i * 4 + 1] = b1 + off;
  cob[(size_t)i * 4 + 2] = b2 + off; cob[(size_t)i * 4 + 3] = b3 + off;
}

// ---------------- NMS: register-resident, 1024 thr, 2 barriers/iter ----------
__global__ __launch_bounds__(1024) void k_nms(
    const float* __restrict__ cbox, const float* __restrict__ cscore,
    const float* __restrict__ ccls, float* __restrict__ out) {
  const int n = blockIdx.x;
  const int tid = threadIdx.x;
  const int wid = tid >> 6, lane = tid & 63;
  __shared__ float redV[16];
  __shared__ int redJ[16];
  __shared__ float sOB[10];  // obx(4), area, bx(4), cls

  float sc[5], bxr[5][4], obr[5][4], ar[5], cl[5];
#pragma unroll
  for (int q = 0; q < 5; ++q) {
    int j = q * 1024 + tid;
    if (j < NCAND) {
      size_t g = (size_t)n * NCAND + j;
      sc[q] = cscore[g];
      float4 b = *(const float4*)(cbox + g * 4);
      float cc = ccls[g];
      float off = cc * 1e4f;
      cl[q] = cc;
      bxr[q][0] = b.x; bxr[q][1] = b.y; bxr[q][2] = b.z; bxr[q][3] = b.w;
      obr[q][0] = b.x + off; obr[q][1] = b.y + off;
      obr[q][2] = b.z + off; obr[q][3] = b.w + off;
      ar[q] = fmaxf(obr[q][2] - obr[q][0], 0.f) * fmaxf(obr[q][3] - obr[q][1], 0.f);
    } else {
      sc[q] = -1.f; cl[q] = 0.f;
      bxr[q][0] = bxr[q][1] = bxr[q][2] = bxr[q][3] = 0.f;
      obr[q][0] = 1e30f; obr[q][1] = 1e30f; obr[q][2] = -1e30f; obr[q][3] = -1e30f;
      ar[q] = 0.f;
    }
  }

  for (int it = 0; it < MAXDET; ++it) {
    float mv = sc[0]; int mj = tid;
#pragma unroll
    for (int q = 1; q < 5; ++q) {
      if (sc[q] > mv) { mv = sc[q]; mj = q * 1024 + tid; }
    }
#pragma unroll
    for (int off = 1; off < 64; off <<= 1) {
      float ov = __shfl_xor(mv, off);
      int oj = __shfl_xor(mj, off);
      if (ov > mv || (ov == mv && oj < mj)) { mv = ov; mj = oj; }
    }
    if (lane == 0) { redV[wid] = mv; redJ[wid] = mj; }
    __syncthreads();
    float bv = redV[0]; int bj = redJ[0];
#pragma unroll
    for (int w = 1; w < 16; ++w) {
      float v2 = redV[w]; int j2 = redJ[w];
      if (v2 > bv || (v2 == bv && j2 < bj)) { bv = v2; bj = j2; }
    }
    const bool owner = ((bj & 1023) == tid);
    if (owner) {
      int q = bj >> 10;
      sOB[0] = obr[q][0]; sOB[1] = obr[q][1]; sOB[2] = obr[q][2]; sOB[3] = obr[q][3];
      sOB[4] = ar[q];
      sOB[5] = bxr[q][0]; sOB[6] = bxr[q][1]; sOB[7] = bxr[q][2]; sOB[8] = bxr[q][3];
      sOB[9] = cl[q];
    }
    __syncthreads();
    const bool valid = bv > 0.f;
    if (valid) {
      float ox1 = sOB[0], oy1 = sOB[1], ox2 = sOB[2], oy2 = sOB[3], ai = sOB[4];
#pragma unroll
      for (int q = 0; q < 5; ++q) {
        int j = q * 1024 + tid;
        float iw = fmaxf(fminf(ox2, obr[q][2]) - fmaxf(ox1, obr[q][0]), 0.f);
        float ih = fmaxf(fminf(oy2, obr[q][3]) - fmaxf(oy1, obr[q][1]), 0.f);
        float inter = iw * ih;
        float iou = inter / fmaxf(ai + ar[q] - inter, 1e-6f);
        if (iou > 0.6f || j == bj) sc[q] = 0.f;
      }
      if (owner) {
        float* o = out + ((size_t)n * MAXDET + it) * 6;
        o[0] = sOB[5]; o[1] = sOB[6]; o[2] = sOB[7]; o[3] = sOB[8];
        o[4] = bv; o[5] = sOB[9];
      }
    } else if (tid == 0) {
      float* o = out + ((size_t)n * MAXDET + it) * 6;
      o[0] = o[1] = o[2] = o[3] = o[4] = o[5] = 0.f;
    }
  }
}

// ---------------- host orchestration -----------------------------------------
extern "C" void kernel_launch(void* const* d_in, const int* in_sizes, int n_in,
                              void* d_out, int out_size, void* d_ws, size_t ws_size,
                              hipStream_t stream) {
  FeatPtrs fp;
  for (int i = 0; i < 5; ++i) fp.p[i] = (const float*)d_in[i];
  const float* cls_w = (const float*)d_in[5];
  const float* cls_b = (const float*)d_in[6];
  const float* cls_gs = (const float*)d_in[7];
  const float* cls_gb = (const float*)d_in[8];
  const float* box_w = (const float*)d_in[9];
  const float* box_b = (const float*)d_in[10];
  const float* box_gs = (const float*)d_in[11];
  const float* box_gb = (const float*)d_in[12];
  const float* score_w = (const float*)d_in[13];
  const float* score_b = (const float*)d_in[14];
  const float* bbox_w = (const float*)d_in[15];
  const float* bbox_b = (const float*)d_in[16];
  const float* ctr_w = (const float*)d_in[17];
  const float* ctr_b = (const float*)d_in[18];
  const float* scales = (const float*)d_in[19];

  float* ws = (float*)d_ws;
  const size_t A_off    = 0;           // 10,376,704
  const size_t B_off    = 10376704;    // 10,376,704 (also feats-transpose FT)
  const size_t WTh_off  = 20753408;    // 1,179,648
  const size_t WTl_off  = 21933056;    // 1,179,648
  const size_t WSh_off  = 23112704;    // 147,456
  const size_t WSl_off  = 23260160;    // 147,456
  const size_t WBh_off  = 23407616;    // 73,728
  const size_t WBl_off  = 23481344;    // 73,728
  const size_t PART_off = 23555072;    // 176,640 (88,320 doubles)
  const size_t CAB_off  = 23731712;    // 5,120
  const size_t CSC_off  = 23736832;    // 10,000
  const size_t CCL_off  = 23746832;    // 10,000
  const size_t GAI_off  = 23756832;    // 10,000
  const size_t H1_off   = 23766832;    // 10,240
  const size_t H2_off   = 23777072;    // 40,960
  const size_t CNT_off  = 23818032;    // 32
  const size_t CTL_off  = 23818064;    // 32
  const size_t EQV_off  = 23818096;    // 20,480
  const size_t EQI_off  = 23838576;    // 20,480
  const size_t LG_off   = A_off + 0;
  const size_t SF_off   = A_off + 4000000;
  const size_t RG_off   = A_off + 7300000;
  const size_t BX_off   = A_off + 7700000;
  const size_t CBX_off  = A_off + 7900000;
  const size_t COB_off  = A_off + 7950000;

  float* A = ws + A_off;
  float* B = ws + B_off;
  _Float16* WTh = (_Float16*)(ws + WTh_off);
  _Float16* WTl = (_Float16*)(ws + WTl_off);
  _Float16* WSh = (_Float16*)(ws + WSh_off);
  _Float16* WSl = (_Float16*)(ws + WSl_off);
  _Float16* WBh = (_Float16*)(ws + WBh_off);
  _Float16* WBl = (_Float16*)(ws + WBl_off);
  double* PART = (double*)(ws + PART_off);
  float* CAB = ws + CAB_off;
  float* CSC = ws + CSC_off;
  float* CCL = ws + CCL_off;
  int* GAI = (int*)(ws + GAI_off);
  unsigned* H1 = (unsigned*)(ws + H1_off);
  unsigned* H2 = (unsigned*)(ws + H2_off);
  unsigned* CNT = (unsigned*)(ws + CNT_off);
  unsigned* CTL = (unsigned*)(ws + CTL_off);
  float* EQV = ws + EQV_off;
  unsigned* EQI = (unsigned*)(ws + EQI_off);
  float* LG = ws + LG_off;
  float* SF = ws + SF_off;
  float* RG = ws + RG_off;
  float* BX = ws + BX_off;
  float* CBX = ws + CBX_off;
  float* COB = ws + COB_off;

  hipMemsetAsync(CSC, 0, (CTL_off + 32 - CSC_off) * sizeof(float), stream);

  dim3 blk(256);
  for (int ll = 0; ll < 4; ++ll)
    hipLaunchKernelGGL(k_rep, dim3(2304), blk, 0, stream,
                       cls_w + (size_t)ll * 589824, (const float*)nullptr,
                       WTh + (size_t)ll * 589824, WTl + (size_t)ll * 589824, 256, 256);
  hipLaunchKernelGGL(k_rep, dim3(1152), blk, 0, stream, score_w, ctr_w, WSh, WSl, 80, 128);
  hipLaunchKernelGGL(k_rep, dim3(576), blk, 0, stream, bbox_w, (const float*)nullptr,
                     WBh, WBl, 4, 64);

  hipLaunchKernelGGL(k_tf, dim3(319, 2), blk, 0, stream, fp, B);

  dim3 gC(345, 1, 2);
  // ---- cls tower
  hipLaunchKernelGGL((k_cmf<false, true, false, 4>), gC, blk, 0, stream,
                     B, WTh, WTl, cls_b, (const float*)nullptr, CAB, A, 256, 256, PART);
  hipLaunchKernelGGL(k_coef, dim3(320), blk, 0, stream, PART, cls_gs, cls_gb, CAB);
  hipLaunchKernelGGL((k_cmf<true, true, false, 4>), gC, blk, 0, stream,
                     A, WTh + 589824, WTl + 589824, cls_b + 256, (const float*)nullptr, CAB, B, 256, 256, PART);
  hipLaunchKernelGGL(k_coef, dim3(320), blk, 0, stream, PART, cls_gs + 256, cls_gb + 256, CAB);
  hipLaunchKernelGGL((k_cmf<true, true, false, 4>), gC, blk, 0, stream,
                     B, WTh + 2 * 589824, WTl + 2 * 589824, cls_b + 512, (const float*)nullptr, CAB, A, 256, 256, PART);
  hipLaunchKernelGGL(k_coef, dim3(320), blk, 0, stream, PART, cls_gs + 512, cls_gb + 512, CAB);
  hipLaunchKernelGGL((k_cmf<true, true, false, 4>), gC, blk, 0, stream,
                     A, WTh + 3 * 589824, WTl + 3 * 589824, cls_b + 768, (const float*)nullptr, CAB, B, 256, 256, PART);
  hipLaunchKernelGGL(k_coef, dim3(320), blk, 0, stream, PART, cls_gs + 768, cls_gb + 768, CAB);

  // ---- score+ctr head: B -> LG (in A)
  hipLaunchKernelGGL((k_cmf<true, false, true, 2>), gC, blk, 0, stream,
                     B, WSh, WSl, score_b, ctr_b, CAB, LG, 96, 81, (double*)nullptr);

  // ---- scores + exact top-1000
  hipLaunchKernelGGL(k_dscore, dim3(12667), blk, 0, stream, LG, SF);
  hipLaunchKernelGGL(k_hist1, dim3(128, 10), blk, 0, stream, SF, H1);
  hipLaunchKernelGGL(k_resolve1, dim3(10), blk, 0, stream, H1, CTL);
  hipLaunchKernelGGL(k_hist2, dim3(128, 10), blk, 0, stream, SF, CTL, H2);
  hipLaunchKernelGGL(k_resolve2, dim3(10), blk, 0, stream, H2, CTL, CTL);
  hipLaunchKernelGGL(k_compact, dim3(128, 10), blk, 0, stream, SF, CTL, CNT, EQV, EQI, CSC, CCL, GAI);
  hipLaunchKernelGGL(k_eq, dim3(10), blk, 0, stream, EQV, EQI, CNT, CSC, CCL, GAI);

  // ---- box tower weights + re-transpose feats
  for (int ll = 0; ll < 4; ++ll)
    hipLaunchKernelGGL(k_rep, dim3(2304), blk, 0, stream,
                       box_w + (size_t)ll * 589824, (const float*)nullptr,
                       WTh + (size_t)ll * 589824, WTl + (size_t)ll * 589824, 256, 256);
  hipLaunchKernelGGL(k_tf, dim3(319, 2), blk, 0, stream, fp, B);

  // ---- box tower
  hipLaunchKernelGGL((k_cmf<false, true, false, 4>), gC, blk, 0, stream,
                     B, WTh, WTl, box_b, (const float*)nullptr, CAB, A, 256, 256, PART);
  hipLaunchKernelGGL(k_coef, dim3(320), blk, 0, stream, PART, box_gs, box_gb, CAB);
  hipLaunchKernelGGL((k_cmf<true, true, false, 4>), gC, blk, 0, stream,
                     A, WTh + 589824, WTl + 589824, box_b + 256, (const float*)nullptr, CAB, B, 256, 256, PART);
  hipLaunchKernelGGL(k_coef, dim3(320), blk, 0, stream, PART, box_gs + 256, box_gb + 256, CAB);
  hipLaunchKernelGGL((k_cmf<true, true, false, 4>), gC, blk, 0, stream,
                     B, WTh + 2 * 589824, WTl + 2 * 589824, box_b + 512, (const float*)nullptr, CAB, A, 256, 256, PART);
  hipLaunchKernelGGL(k_coef, dim3(320), blk, 0, stream, PART, box_gs + 512, box_gb + 512, CAB);
  hipLaunchKernelGGL((k_cmf<true, true, false, 4>), gC, blk, 0, stream,
                     A, WTh + 3 * 589824, WTl + 3 * 589824, box_b + 768, (const float*)nullptr, CAB, B, 256, 256, PART);
  hipLaunchKernelGGL(k_coef, dim3(320), blk, 0, stream, PART, box_gs + 768, box_gb + 768, CAB);

  // ---- bbox head: B -> RG (in A)
  hipLaunchKernelGGL((k_cmf<true, false, false, 1>), gC, blk, 0, stream,
                     B, WBh, WBl, bbox_b, (const float*)nullptr, CAB, RG, 8, 4, (double*)nullptr);

  // ---- boxes, gather, NMS
  hipLaunchKernelGGL(k_dbox, dim3(159), blk, 0, stream, RG, scales, BX);
  hipLaunchKernelGGL(k_gather, dim3(40), blk, 0, stream, GAI, CCL, BX, CBX, COB);
  hipLaunchKernelGGL(k_nms, dim3(2), dim3(1024), 0, stream, CBX, CSC, CCL, (float*)d_out);
}